// Round 1
// baseline (703.141 us; speedup 1.0000x reference)
//
#include <hip/hip_runtime.h>

#define FRLEN 44100
#define FR2 22050
#define LSND 882000
#define PADLEN (LSND + FRLEN)   // 926100
#define TSTEPS 2048
#define ROWS 4
#define NJ4 (FRLEN/4)           // 11025

__device__ __forceinline__ float sigmoidf_(float x){ return 1.0f/(1.0f + __expf(-x)); }

__global__ void k_prep(const float* __restrict__ sound, float* __restrict__ padded){
  int stride = gridDim.x*blockDim.x;
  for (int i = blockIdx.x*blockDim.x + threadIdx.x; i < PADLEN; i += stride){
    int s = i - FR2;
    padded[i] = (s >= 0 && s < LSND) ? fabsf(sound[s]) : 0.0f;
  }
}

__global__ __launch_bounds__(256) void k_gi(const float* __restrict__ padded,
                     const int* __restrict__ alpha,
                     const float* __restrict__ w,
                     float* __restrict__ gi_out){
  const int tid = threadIdx.x;
  const int row0 = blockIdx.x * ROWS;
  int base[ROWS];
#pragma unroll
  for (int r = 0; r < ROWS; ++r) base[r] = alpha[row0 + r];
  float acc[ROWS][9];
#pragma unroll
  for (int r = 0; r < ROWS; ++r)
#pragma unroll
    for (int k = 0; k < 9; ++k) acc[r][k] = 0.0f;

  for (int jj = tid; jj < NJ4; jj += 256){
    const int j = jj*4;
    float f[ROWS][4];
#pragma unroll
    for (int r = 0; r < ROWS; ++r){
      const float* p = padded + base[r] + j;
#pragma unroll
      for (int e = 0; e < 4; ++e) f[r][e] = p[e];
    }
#pragma unroll
    for (int k = 0; k < 9; ++k){
      const float4 wv = *reinterpret_cast<const float4*>(w + k*FRLEN + j);
#pragma unroll
      for (int r = 0; r < ROWS; ++r){
        acc[r][k] = fmaf(f[r][0], wv.x, acc[r][k]);
        acc[r][k] = fmaf(f[r][1], wv.y, acc[r][k]);
        acc[r][k] = fmaf(f[r][2], wv.z, acc[r][k]);
        acc[r][k] = fmaf(f[r][3], wv.w, acc[r][k]);
      }
    }
  }
  // wave butterfly reduce (64 lanes)
#pragma unroll
  for (int m = 32; m >= 1; m >>= 1){
#pragma unroll
    for (int r = 0; r < ROWS; ++r)
#pragma unroll
      for (int k = 0; k < 9; ++k)
        acc[r][k] += __shfl_xor(acc[r][k], m, 64);
  }
  __shared__ float red[4][36];
  const int wv_ = tid >> 6, ln = tid & 63;
  if (ln == 0){
#pragma unroll
    for (int r = 0; r < ROWS; ++r)
#pragma unroll
      for (int k = 0; k < 9; ++k) red[wv_][r*9+k] = acc[r][k];
  }
  __syncthreads();
  if (tid < 36){
    float s = red[0][tid] + red[1][tid] + red[2][tid] + red[3][tid];
    gi_out[row0*9 + tid] = s;   // rows are contiguous: (row0 + tid/9)*9 + tid%9
  }
}

__global__ void k_epi(const float* __restrict__ gi_in, const int* __restrict__ alpha,
    const float* __restrict__ gbih, const float* __restrict__ gbhh,
    const float* __restrict__ c2w, const float* __restrict__ c2b,
    const float* __restrict__ c3w, const float* __restrict__ c3b,
    const float* __restrict__ lw, const float* __restrict__ lb,
    const float* __restrict__ wih, const float* __restrict__ bih, const float* __restrict__ bhh,
    float* __restrict__ pre){
  int t = blockIdx.x*blockDim.x + threadIdx.x;
  if (t >= TSTEPS) return;
  float gi[9];
#pragma unroll
  for (int k = 0; k < 9; ++k) gi[k] = gi_in[t*9+k] + gbih[k];
  float h[3];
#pragma unroll
  for (int q = 0; q < 3; ++q){
    float rr = sigmoidf_(gi[q]   + gbhh[q]);
    float zz = sigmoidf_(gi[3+q] + gbhh[3+q]);
    float nn = tanhf(gi[6+q] + rr*gbhh[6+q]);
    h[q] = (1.0f - zz)*nn;
  }
  // conv2 (1->32, k=3, pad=1, H=3) fused with conv3 (32->16, k=3, H=3->1)
  float feat[16];
#pragma unroll
  for (int c = 0; c < 16; ++c) feat[c] = c3b[c];
  for (int ic = 0; ic < 32; ++ic){
    float w0 = c2w[ic*3+0], w1 = c2w[ic*3+1], w2 = c2w[ic*3+2], bb = c2b[ic];
    float x0 = fmaxf(bb + h[0]*w1 + h[1]*w2, 0.0f);
    float x1 = fmaxf(bb + h[0]*w0 + h[1]*w1 + h[2]*w2, 0.0f);
    float x2_ = fmaxf(bb + h[1]*w0 + h[2]*w1, 0.0f);
#pragma unroll
    for (int c = 0; c < 16; ++c){
      const float* wp = c3w + (c*32+ic)*3;
      feat[c] += x0*wp[0] + x1*wp[1] + x2_*wp[2];
    }
  }
  float interval = (float)(t == 0 ? alpha[0] : (alpha[t] - alpha[t-1]));
  float xin[10];
#pragma unroll
  for (int k = 0; k < 10; ++k){
    float s = lb[k] + interval*lw[k*17];
#pragma unroll
    for (int j = 0; j < 16; ++j) s = fmaf(feat[j], lw[k*17+1+j], s);
    xin[k] = s;
  }
  // LSTM input projection + both biases, precomputed per step
#pragma unroll
  for (int k = 0; k < 40; ++k){
    float s = bih[k] + bhh[k];
#pragma unroll
    for (int i = 0; i < 10; ++i) s = fmaf(xin[i], wih[k*10+i], s);
    pre[t*40+k] = s;
  }
}

__global__ void k_lstm(const float* __restrict__ pre, const float* __restrict__ whh,
                       const float* __restrict__ l1w, const float* __restrict__ l1b,
                       const float* __restrict__ l2w, const float* __restrict__ l2b,
                       float* __restrict__ out){
  const int lane = threadIdx.x;       // 64 threads, 1 wave
  const bool gk = lane < 40;
  float w[10];
#pragma unroll
  for (int i = 0; i < 10; ++i) w[i] = gk ? whh[lane*10+i] : 0.0f;
  // branchless activation: lanes 20..29 (gate g) use tanh, others sigmoid
  const bool is_g = (lane >= 20 && lane < 30);
  const float ac = is_g ? -2.0f : -1.0f;
  const float s2 = is_g ?  2.0f : 1.0f;
  const float s3 = is_g ? -1.0f : 0.0f;
  float h[10];
#pragma unroll
  for (int i = 0; i < 10; ++i) h[i] = 0.0f;
  float c = 0.0f;
  const int jl = (lane < 10) ? lane : 0;
  float p0 = gk ? pre[lane] : 0.0f;           // 2-deep register prefetch
  float p1 = gk ? pre[40+lane] : 0.0f;
  for (int t = 0; t < TSTEPS; ++t){
    float g = p0;
    p0 = p1;
    p1 = (gk && (t+2) < TSTEPS) ? pre[(t+2)*40+lane] : 0.0f;
#pragma unroll
    for (int i = 0; i < 10; ++i) g = fmaf(h[i], w[i], g);
    float e = __expf(g*ac);
    float act = fmaf(__builtin_amdgcn_rcpf(1.0f+e), s2, s3);
    float ia_ = __shfl(act, jl,      64);
    float fa_ = __shfl(act, jl + 10, 64);
    float ga_ = __shfl(act, jl + 20, 64);
    float oa_ = __shfl(act, jl + 30, 64);
    c = fmaf(fa_, c, ia_*ga_);                 // valid in lanes 0..9
    float e2 = __expf(-2.0f*c);
    float th = fmaf(__builtin_amdgcn_rcpf(1.0f+e2), 2.0f, -1.0f);
    float hn = oa_*th;
#pragma unroll
    for (int i = 0; i < 10; ++i) h[i] = __shfl(hn, i, 64);
  }
  // head: y = relu(h @ l1w.T + l1b); out = sigmoid(y @ l2w.T + l2b)
  float z = 0.0f;
  if (lane < 32){
    float s = l1b[lane];
#pragma unroll
    for (int i = 0; i < 10; ++i) s = fmaf(h[i], l1w[lane*10+i], s);
    z = fmaxf(s, 0.0f) * l2w[lane];
  }
#pragma unroll
  for (int m = 32; m >= 1; m >>= 1) z += __shfl_xor(z, m, 64);
  if (lane == 0) out[0] = sigmoidf_(z + l2b[0]);
}

extern "C" void kernel_launch(void* const* d_in, const int* in_sizes, int n_in,
                              void* d_out, int out_size, void* d_ws, size_t ws_size,
                              hipStream_t stream){
  const float* sound     = (const float*)d_in[0];
  const int*   alpha     = (const int*)  d_in[1];
  const float* gru_w_ih  = (const float*)d_in[2];
  const float* gru_b_ih  = (const float*)d_in[3];
  const float* gru_b_hh  = (const float*)d_in[4];
  const float* conv2_w   = (const float*)d_in[5];
  const float* conv2_b   = (const float*)d_in[6];
  const float* conv3_w   = (const float*)d_in[7];
  const float* conv3_b   = (const float*)d_in[8];
  const float* lin_w     = (const float*)d_in[9];
  const float* lin_b     = (const float*)d_in[10];
  const float* lstm_w_ih = (const float*)d_in[11];
  const float* lstm_w_hh = (const float*)d_in[12];
  const float* lstm_b_ih = (const float*)d_in[13];
  const float* lstm_b_hh = (const float*)d_in[14];
  const float* lin1_w    = (const float*)d_in[15];
  const float* lin1_b    = (const float*)d_in[16];
  const float* lin2_w    = (const float*)d_in[17];
  const float* lin2_b    = (const float*)d_in[18];

  float* padded = (float*)d_ws;           // PADLEN f32
  float* gi     = padded + PADLEN;        // T*9 f32
  float* pre    = gi + TSTEPS*9;          // T*40 f32

  hipLaunchKernelGGL(k_prep, dim3(2048), dim3(256), 0, stream, sound, padded);
  hipLaunchKernelGGL(k_gi, dim3(TSTEPS/ROWS), dim3(256), 0, stream, padded, alpha, gru_w_ih, gi);
  hipLaunchKernelGGL(k_epi, dim3(TSTEPS/256), dim3(256), 0, stream,
                     gi, alpha, gru_b_ih, gru_b_hh, conv2_w, conv2_b, conv3_w, conv3_b,
                     lin_w, lin_b, lstm_w_ih, lstm_b_ih, lstm_b_hh, pre);
  hipLaunchKernelGGL(k_lstm, dim3(1), dim3(64), 0, stream,
                     pre, lstm_w_hh, lin1_w, lin1_b, lin2_w, lin2_b, (float*)d_out);
}

// Round 2
// 654.204 us; speedup vs baseline: 1.0748x; 1.0748x over previous
//
#include <hip/hip_runtime.h>

#define FRLEN 44100
#define FR2 22050
#define LSND 882000
#define PADLEN (LSND + FRLEN)   // 926100
#define TSTEPS 2048
#define ROWS 4
#define NJ4 (FRLEN/4)           // 11025

__device__ __forceinline__ float sigmoidf_(float x){ return 1.0f/(1.0f + __expf(-x)); }

__global__ void k_prep(const float* __restrict__ sound, float* __restrict__ padded){
  int stride = gridDim.x*blockDim.x;
  for (int i = blockIdx.x*blockDim.x + threadIdx.x; i < PADLEN; i += stride){
    int s = i - FR2;
    padded[i] = (s >= 0 && s < LSND) ? fabsf(sound[s]) : 0.0f;
  }
}

__global__ __launch_bounds__(256) void k_gi(const float* __restrict__ padded,
                     const int* __restrict__ alpha,
                     const float* __restrict__ w,
                     float* __restrict__ gi_out){
  const int tid = threadIdx.x;
  const int row0 = blockIdx.x * ROWS;
  int base[ROWS];
#pragma unroll
  for (int r = 0; r < ROWS; ++r) base[r] = alpha[row0 + r];
  float acc[ROWS][9];
#pragma unroll
  for (int r = 0; r < ROWS; ++r)
#pragma unroll
    for (int k = 0; k < 9; ++k) acc[r][k] = 0.0f;

  for (int jj = tid; jj < NJ4; jj += 256){
    const int j = jj*4;
    float f[ROWS][4];
#pragma unroll
    for (int r = 0; r < ROWS; ++r){
      const float* p = padded + base[r] + j;
#pragma unroll
      for (int e = 0; e < 4; ++e) f[r][e] = p[e];
    }
#pragma unroll
    for (int k = 0; k < 9; ++k){
      const float4 wv = *reinterpret_cast<const float4*>(w + k*FRLEN + j);
#pragma unroll
      for (int r = 0; r < ROWS; ++r){
        acc[r][k] = fmaf(f[r][0], wv.x, acc[r][k]);
        acc[r][k] = fmaf(f[r][1], wv.y, acc[r][k]);
        acc[r][k] = fmaf(f[r][2], wv.z, acc[r][k]);
        acc[r][k] = fmaf(f[r][3], wv.w, acc[r][k]);
      }
    }
  }
  // wave butterfly reduce (64 lanes)
#pragma unroll
  for (int m = 32; m >= 1; m >>= 1){
#pragma unroll
    for (int r = 0; r < ROWS; ++r)
#pragma unroll
      for (int k = 0; k < 9; ++k)
        acc[r][k] += __shfl_xor(acc[r][k], m, 64);
  }
  __shared__ float red[4][36];
  const int wv_ = tid >> 6, ln = tid & 63;
  if (ln == 0){
#pragma unroll
    for (int r = 0; r < ROWS; ++r)
#pragma unroll
      for (int k = 0; k < 9; ++k) red[wv_][r*9+k] = acc[r][k];
  }
  __syncthreads();
  if (tid < 36){
    float s = red[0][tid] + red[1][tid] + red[2][tid] + red[3][tid];
    gi_out[row0*9 + tid] = s;
  }
}

__global__ void k_epi(const float* __restrict__ gi_in, const int* __restrict__ alpha,
    const float* __restrict__ gbih, const float* __restrict__ gbhh,
    const float* __restrict__ c2w, const float* __restrict__ c2b,
    const float* __restrict__ c3w, const float* __restrict__ c3b,
    const float* __restrict__ lw, const float* __restrict__ lb,
    const float* __restrict__ wih, const float* __restrict__ bih, const float* __restrict__ bhh,
    float* __restrict__ pre){
  int t = blockIdx.x*blockDim.x + threadIdx.x;
  if (t >= TSTEPS) return;
  float gi[9];
#pragma unroll
  for (int k = 0; k < 9; ++k) gi[k] = gi_in[t*9+k] + gbih[k];
  float h[3];
#pragma unroll
  for (int q = 0; q < 3; ++q){
    float rr = sigmoidf_(gi[q]   + gbhh[q]);
    float zz = sigmoidf_(gi[3+q] + gbhh[3+q]);
    float nn = tanhf(gi[6+q] + rr*gbhh[6+q]);
    h[q] = (1.0f - zz)*nn;
  }
  // conv2 (1->32, k=3, pad=1, H=3) fused with conv3 (32->16, k=3, H=3->1)
  float feat[16];
#pragma unroll
  for (int c = 0; c < 16; ++c) feat[c] = c3b[c];
  for (int ic = 0; ic < 32; ++ic){
    float w0 = c2w[ic*3+0], w1 = c2w[ic*3+1], w2 = c2w[ic*3+2], bb = c2b[ic];
    float x0 = fmaxf(bb + h[0]*w1 + h[1]*w2, 0.0f);
    float x1 = fmaxf(bb + h[0]*w0 + h[1]*w1 + h[2]*w2, 0.0f);
    float x2_ = fmaxf(bb + h[1]*w0 + h[2]*w1, 0.0f);
#pragma unroll
    for (int c = 0; c < 16; ++c){
      const float* wp = c3w + (c*32+ic)*3;
      feat[c] += x0*wp[0] + x1*wp[1] + x2_*wp[2];
    }
  }
  float interval = (float)(t == 0 ? alpha[0] : (alpha[t] - alpha[t-1]));
  float xin[10];
#pragma unroll
  for (int k = 0; k < 10; ++k){
    float s = lb[k] + interval*lw[k*17];
#pragma unroll
    for (int j = 0; j < 16; ++j) s = fmaf(feat[j], lw[k*17+1+j], s);
    xin[k] = s;
  }
  // LSTM input projection + both biases, precomputed per step.
  // Layout: pre[t*40 + unit*4 + gate]  (gate: 0=i,1=f,2=g,3=o) -> one float4 per unit
#pragma unroll
  for (int k = 0; k < 40; ++k){
    float s = bih[k] + bhh[k];
#pragma unroll
    for (int i = 0; i < 10; ++i) s = fmaf(xin[i], wih[k*10+i], s);
    const int gate = k / 10, unit = k % 10;
    pre[t*40 + unit*4 + gate] = s;
  }
}

// One wave. Lane j (j = lane%10) owns hidden unit j: computes all 4 of its
// gates locally (no cross-lane exchange), h broadcast via readlane -> SGPRs.
__global__ __launch_bounds__(64) void k_lstm(const float* __restrict__ pre, const float* __restrict__ whh,
                       const float* __restrict__ l1w, const float* __restrict__ l1b,
                       const float* __restrict__ l2w, const float* __restrict__ l2b,
                       float* __restrict__ out){
  const int lane = threadIdx.x & 63;
  const int j = lane % 10;
  float wi[10], wf[10], wg[10], wo[10];
#pragma unroll
  for (int i = 0; i < 10; ++i){
    wi[i] = whh[( 0 + j)*10 + i];
    wf[i] = whh[(10 + j)*10 + i];
    wg[i] = whh[(20 + j)*10 + i];
    wo[i] = whh[(30 + j)*10 + i];
  }
  float hs[10];
#pragma unroll
  for (int i = 0; i < 10; ++i) hs[i] = 0.0f;
  float c = 0.0f;
  const float4* __restrict__ pr = (const float4*)pre;   // pr[t*10 + j]
  float4 q0 = pr[ 0 + j];
  float4 q1 = pr[10 + j];
  float4 q2 = pr[20 + j];
  float4 q3 = pr[30 + j];
#pragma unroll 4
  for (int t = 0; t < TSTEPS; ++t){
    float4 p = q0; q0 = q1; q1 = q2; q2 = q3;
    if (t + 4 < TSTEPS) q3 = pr[(t+4)*10 + j];
    float gi_ = p.x, gf_ = p.y, gg_ = p.z, go_ = p.w;
#pragma unroll
    for (int i = 0; i < 10; ++i){
      gi_ = fmaf(hs[i], wi[i], gi_);
      gf_ = fmaf(hs[i], wf[i], gf_);
      gg_ = fmaf(hs[i], wg[i], gg_);
      go_ = fmaf(hs[i], wo[i], go_);
    }
    float ai = __builtin_amdgcn_rcpf(1.0f + __expf(-gi_));
    float af = __builtin_amdgcn_rcpf(1.0f + __expf(-gf_));
    float ag = fmaf(__builtin_amdgcn_rcpf(1.0f + __expf(-2.0f*gg_)), 2.0f, -1.0f);
    float ao = __builtin_amdgcn_rcpf(1.0f + __expf(-go_));
    c = fmaf(af, c, ai*ag);
    float th = fmaf(__builtin_amdgcn_rcpf(1.0f + __expf(-2.0f*c)), 2.0f, -1.0f);
    float hn = ao*th;
#pragma unroll
    for (int i = 0; i < 10; ++i)
      hs[i] = __int_as_float(__builtin_amdgcn_readlane(__float_as_int(hn), i));
  }
  // head: y = relu(h @ l1w.T + l1b); out = sigmoid(y @ l2w.T + l2b)
  float z = 0.0f;
  if (lane < 32){
    float s = l1b[lane];
#pragma unroll
    for (int i = 0; i < 10; ++i) s = fmaf(hs[i], l1w[lane*10+i], s);
    z = fmaxf(s, 0.0f) * l2w[lane];
  }
#pragma unroll
  for (int m = 32; m >= 1; m >>= 1) z += __shfl_xor(z, m, 64);
  if (lane == 0) out[0] = sigmoidf_(z + l2b[0]);
}

extern "C" void kernel_launch(void* const* d_in, const int* in_sizes, int n_in,
                              void* d_out, int out_size, void* d_ws, size_t ws_size,
                              hipStream_t stream){
  const float* sound     = (const float*)d_in[0];
  const int*   alpha     = (const int*)  d_in[1];
  const float* gru_w_ih  = (const float*)d_in[2];
  const float* gru_b_ih  = (const float*)d_in[3];
  const float* gru_b_hh  = (const float*)d_in[4];
  const float* conv2_w   = (const float*)d_in[5];
  const float* conv2_b   = (const float*)d_in[6];
  const float* conv3_w   = (const float*)d_in[7];
  const float* conv3_b   = (const float*)d_in[8];
  const float* lin_w     = (const float*)d_in[9];
  const float* lin_b     = (const float*)d_in[10];
  const float* lstm_w_ih = (const float*)d_in[11];
  const float* lstm_w_hh = (const float*)d_in[12];
  const float* lstm_b_ih = (const float*)d_in[13];
  const float* lstm_b_hh = (const float*)d_in[14];
  const float* lin1_w    = (const float*)d_in[15];
  const float* lin1_b    = (const float*)d_in[16];
  const float* lin2_w    = (const float*)d_in[17];
  const float* lin2_b    = (const float*)d_in[18];

  float* padded = (float*)d_ws;           // PADLEN f32
  float* gi     = padded + PADLEN;        // T*9 f32
  float* pre    = gi + TSTEPS*9;          // T*40 f32

  hipLaunchKernelGGL(k_prep, dim3(2048), dim3(256), 0, stream, sound, padded);
  hipLaunchKernelGGL(k_gi, dim3(TSTEPS/ROWS), dim3(256), 0, stream, padded, alpha, gru_w_ih, gi);
  hipLaunchKernelGGL(k_epi, dim3(TSTEPS/256), dim3(256), 0, stream,
                     gi, alpha, gru_b_ih, gru_b_hh, conv2_w, conv2_b, conv3_w, conv3_b,
                     lin_w, lin_b, lstm_w_ih, lstm_b_ih, lstm_b_hh, pre);
  hipLaunchKernelGGL(k_lstm, dim3(1), dim3(64), 0, stream,
                     pre, lstm_w_hh, lin1_w, lin1_b, lin2_w, lin2_b, (float*)d_out);
}

// Round 3
// 448.158 us; speedup vs baseline: 1.5690x; 1.4598x over previous
//
#include <hip/hip_runtime.h>

#define FRLEN 44100
#define FR2 22050
#define LSND 882000
#define PADLEN (LSND + FRLEN)   // 926100
#define TSTEPS 2048
#define ROWS 4
#define NJ4 (FRLEN/4)           // 11025

typedef _Float16 half4_ __attribute__((ext_vector_type(4)));   // 8 bytes

__device__ __forceinline__ float sigmoidf_(float x){ return 1.0f/(1.0f + __expf(-x)); }

__global__ void k_prep(const float* __restrict__ sound, float* __restrict__ padded){
  int stride = gridDim.x*blockDim.x;
  for (int i = blockIdx.x*blockDim.x + threadIdx.x; i < PADLEN; i += stride){
    int s = i - FR2;
    padded[i] = (s >= 0 && s < LSND) ? fabsf(sound[s]) : 0.0f;
  }
}

__global__ __launch_bounds__(256) void k_gi(const float* __restrict__ padded,
                     const int* __restrict__ alpha,
                     const float* __restrict__ w,
                     float* __restrict__ gi_out){
  const int tid = threadIdx.x;
  const int row0 = blockIdx.x * ROWS;
  int base[ROWS];
#pragma unroll
  for (int r = 0; r < ROWS; ++r) base[r] = alpha[row0 + r];
  float acc[ROWS][9];
#pragma unroll
  for (int r = 0; r < ROWS; ++r)
#pragma unroll
    for (int k = 0; k < 9; ++k) acc[r][k] = 0.0f;

  for (int jj = tid; jj < NJ4; jj += 256){
    const int j = jj*4;
    float f[ROWS][4];
#pragma unroll
    for (int r = 0; r < ROWS; ++r){
      const float* p = padded + base[r] + j;
#pragma unroll
      for (int e = 0; e < 4; ++e) f[r][e] = p[e];
    }
#pragma unroll
    for (int k = 0; k < 9; ++k){
      const float4 wv = *reinterpret_cast<const float4*>(w + k*FRLEN + j);
#pragma unroll
      for (int r = 0; r < ROWS; ++r){
        acc[r][k] = fmaf(f[r][0], wv.x, acc[r][k]);
        acc[r][k] = fmaf(f[r][1], wv.y, acc[r][k]);
        acc[r][k] = fmaf(f[r][2], wv.z, acc[r][k]);
        acc[r][k] = fmaf(f[r][3], wv.w, acc[r][k]);
      }
    }
  }
#pragma unroll
  for (int m = 32; m >= 1; m >>= 1){
#pragma unroll
    for (int r = 0; r < ROWS; ++r)
#pragma unroll
      for (int k = 0; k < 9; ++k)
        acc[r][k] += __shfl_xor(acc[r][k], m, 64);
  }
  __shared__ float red[4][36];
  const int wv_ = tid >> 6, ln = tid & 63;
  if (ln == 0){
#pragma unroll
    for (int r = 0; r < ROWS; ++r)
#pragma unroll
      for (int k = 0; k < 9; ++k) red[wv_][r*9+k] = acc[r][k];
  }
  __syncthreads();
  if (tid < 36){
    float s = red[0][tid] + red[1][tid] + red[2][tid] + red[3][tid];
    gi_out[row0*9 + tid] = s;
  }
}

__global__ void k_epi(const float* __restrict__ gi_in, const int* __restrict__ alpha,
    const float* __restrict__ gbih, const float* __restrict__ gbhh,
    const float* __restrict__ c2w, const float* __restrict__ c2b,
    const float* __restrict__ c3w, const float* __restrict__ c3b,
    const float* __restrict__ lw, const float* __restrict__ lb,
    const float* __restrict__ wih, const float* __restrict__ bih, const float* __restrict__ bhh,
    _Float16* __restrict__ pre){
  int t = blockIdx.x*blockDim.x + threadIdx.x;
  if (t >= TSTEPS) return;
  float gi[9];
#pragma unroll
  for (int k = 0; k < 9; ++k) gi[k] = gi_in[t*9+k] + gbih[k];
  float h[3];
#pragma unroll
  for (int q = 0; q < 3; ++q){
    float rr = sigmoidf_(gi[q]   + gbhh[q]);
    float zz = sigmoidf_(gi[3+q] + gbhh[3+q]);
    float nn = tanhf(gi[6+q] + rr*gbhh[6+q]);
    h[q] = (1.0f - zz)*nn;
  }
  float feat[16];
#pragma unroll
  for (int c = 0; c < 16; ++c) feat[c] = c3b[c];
  for (int ic = 0; ic < 32; ++ic){
    float w0 = c2w[ic*3+0], w1 = c2w[ic*3+1], w2 = c2w[ic*3+2], bb = c2b[ic];
    float x0 = fmaxf(bb + h[0]*w1 + h[1]*w2, 0.0f);
    float x1 = fmaxf(bb + h[0]*w0 + h[1]*w1 + h[2]*w2, 0.0f);
    float x2_ = fmaxf(bb + h[1]*w0 + h[2]*w1, 0.0f);
#pragma unroll
    for (int c = 0; c < 16; ++c){
      const float* wp = c3w + (c*32+ic)*3;
      feat[c] += x0*wp[0] + x1*wp[1] + x2_*wp[2];
    }
  }
  float interval = (float)(t == 0 ? alpha[0] : (alpha[t] - alpha[t-1]));
  float xin[10];
#pragma unroll
  for (int k = 0; k < 10; ++k){
    float s = lb[k] + interval*lw[k*17];
#pragma unroll
    for (int j = 0; j < 16; ++j) s = fmaf(feat[j], lw[k*17+1+j], s);
    xin[k] = s;
  }
  // LSTM input projection + both biases, fp16, layout pre[t*40 + unit*4 + gate]
#pragma unroll
  for (int k = 0; k < 40; ++k){
    float s = bih[k] + bhh[k];
#pragma unroll
    for (int i = 0; i < 10; ++i) s = fmaf(xin[i], wih[k*10+i], s);
    const int gate = k / 10, unit = k % 10;
    pre[t*40 + unit*4 + gate] = (_Float16)s;
  }
}

// 1024 threads: 16 waves stage all of pre (fp16, 160KiB) into LDS; wave 0 scans.
__global__ __launch_bounds__(1024) void k_lstm(const _Float16* __restrict__ pre,
                       const float* __restrict__ whh,
                       const float* __restrict__ l1w, const float* __restrict__ l1b,
                       const float* __restrict__ l2w, const float* __restrict__ l2b,
                       float* __restrict__ out){
  extern __shared__ char smem[];
  // stage: 163840 B = 10240 uint4
  {
    uint4* dst = (uint4*)smem;
    const uint4* src = (const uint4*)pre;
    for (int i = threadIdx.x; i < (TSTEPS*40*2)/16; i += 1024) dst[i] = src[i];
  }
  __syncthreads();
  if (threadIdx.x >= 64) return;

  const int lane = threadIdx.x & 63;
  const int j = lane % 10;
  float wi[10], wf[10], wg[10], wo[10];
#pragma unroll
  for (int i = 0; i < 10; ++i){
    wi[i] = whh[( 0 + j)*10 + i];
    wf[i] = whh[(10 + j)*10 + i];
    wg[i] = whh[(20 + j)*10 + i];
    wo[i] = whh[(30 + j)*10 + i];
  }
  float hs[10];
#pragma unroll
  for (int i = 0; i < 10; ++i) hs[i] = 0.0f;
  float c = 0.0f;
  const half4_* __restrict__ lp = (const half4_*)smem;   // lp[t*10 + j]
  half4_ q0 = lp[ 0 + j];
  half4_ q1 = lp[10 + j];
  half4_ q2 = lp[20 + j];
  half4_ q3 = lp[30 + j];
#pragma unroll 4
  for (int t = 0; t < TSTEPS; ++t){
    half4_ p = q0; q0 = q1; q1 = q2; q2 = q3;
    if (t + 4 < TSTEPS) q3 = lp[(t+4)*10 + j];
    float gi_ = (float)p.x, gf_ = (float)p.y, gg_ = (float)p.z, go_ = (float)p.w;
#pragma unroll
    for (int i = 0; i < 10; ++i){
      gi_ = fmaf(hs[i], wi[i], gi_);
      gf_ = fmaf(hs[i], wf[i], gf_);
      gg_ = fmaf(hs[i], wg[i], gg_);
      go_ = fmaf(hs[i], wo[i], go_);
    }
    float ai = __builtin_amdgcn_rcpf(1.0f + __expf(-gi_));
    float af = __builtin_amdgcn_rcpf(1.0f + __expf(-gf_));
    float ag = fmaf(__builtin_amdgcn_rcpf(1.0f + __expf(-2.0f*gg_)), 2.0f, -1.0f);
    float ao = __builtin_amdgcn_rcpf(1.0f + __expf(-go_));
    c = fmaf(af, c, ai*ag);
    float th = fmaf(__builtin_amdgcn_rcpf(1.0f + __expf(-2.0f*c)), 2.0f, -1.0f);
    float hn = ao*th;
#pragma unroll
    for (int i = 0; i < 10; ++i)
      hs[i] = __int_as_float(__builtin_amdgcn_readlane(__float_as_int(hn), i));
  }
  float z = 0.0f;
  if (lane < 32){
    float s = l1b[lane];
#pragma unroll
    for (int i = 0; i < 10; ++i) s = fmaf(hs[i], l1w[lane*10+i], s);
    z = fmaxf(s, 0.0f) * l2w[lane];
  }
#pragma unroll
  for (int m = 32; m >= 1; m >>= 1) z += __shfl_xor(z, m, 64);
  if (lane == 0) out[0] = sigmoidf_(z + l2b[0]);
}

extern "C" void kernel_launch(void* const* d_in, const int* in_sizes, int n_in,
                              void* d_out, int out_size, void* d_ws, size_t ws_size,
                              hipStream_t stream){
  const float* sound     = (const float*)d_in[0];
  const int*   alpha     = (const int*)  d_in[1];
  const float* gru_w_ih  = (const float*)d_in[2];
  const float* gru_b_ih  = (const float*)d_in[3];
  const float* gru_b_hh  = (const float*)d_in[4];
  const float* conv2_w   = (const float*)d_in[5];
  const float* conv2_b   = (const float*)d_in[6];
  const float* conv3_w   = (const float*)d_in[7];
  const float* conv3_b   = (const float*)d_in[8];
  const float* lin_w     = (const float*)d_in[9];
  const float* lin_b     = (const float*)d_in[10];
  const float* lstm_w_ih = (const float*)d_in[11];
  const float* lstm_w_hh = (const float*)d_in[12];
  const float* lstm_b_ih = (const float*)d_in[13];
  const float* lstm_b_hh = (const float*)d_in[14];
  const float* lin1_w    = (const float*)d_in[15];
  const float* lin1_b    = (const float*)d_in[16];
  const float* lin2_w    = (const float*)d_in[17];
  const float* lin2_b    = (const float*)d_in[18];

  float* padded = (float*)d_ws;                    // PADLEN f32
  float* gi     = padded + PADLEN;                 // T*9 f32
  _Float16* pre = (_Float16*)(gi + TSTEPS*9);      // T*40 fp16 (16B-aligned)

  // allow 160 KiB dynamic LDS for k_lstm (idempotent, non-stream call)
  (void)hipFuncSetAttribute((const void*)k_lstm,
        hipFuncAttributeMaxDynamicSharedMemorySize, TSTEPS*40*2);

  hipLaunchKernelGGL(k_prep, dim3(2048), dim3(256), 0, stream, sound, padded);
  hipLaunchKernelGGL(k_gi, dim3(TSTEPS/ROWS), dim3(256), 0, stream, padded, alpha, gru_w_ih, gi);
  hipLaunchKernelGGL(k_epi, dim3(TSTEPS/256), dim3(256), 0, stream,
                     gi, alpha, gru_b_ih, gru_b_hh, conv2_w, conv2_b, conv3_w, conv3_b,
                     lin_w, lin_b, lstm_w_ih, lstm_b_ih, lstm_b_hh, pre);
  hipLaunchKernelGGL(k_lstm, dim3(1), dim3(1024), TSTEPS*40*2, stream,
                     pre, lstm_w_hh, lin1_w, lin1_b, lin2_w, lin2_b, (float*)d_out);
}

// Round 4
// 331.082 us; speedup vs baseline: 2.1238x; 1.3536x over previous
//
#include <hip/hip_runtime.h>

#define FRLEN 44100
#define FR2 22050
#define LSND 882000
#define PADLEN (LSND + FRLEN)   // 926100
#define TSTEPS 2048
#define ROWS 4
#define NJ4 (FRLEN/4)           // 11025

__device__ __forceinline__ float sigmoidf_(float x){ return 1.0f/(1.0f + __expf(-x)); }

__global__ void k_prep(const float* __restrict__ sound, float* __restrict__ padded){
  int stride = gridDim.x*blockDim.x;
  for (int i = blockIdx.x*blockDim.x + threadIdx.x; i < PADLEN; i += stride){
    int s = i - FR2;
    padded[i] = (s >= 0 && s < LSND) ? fabsf(sound[s]) : 0.0f;
  }
}

__global__ __launch_bounds__(256) void k_gi(const float* __restrict__ padded,
                     const int* __restrict__ alpha,
                     const float* __restrict__ w,
                     float* __restrict__ gi_out){
  const int tid = threadIdx.x;
  const int row0 = blockIdx.x * ROWS;
  int base[ROWS];
#pragma unroll
  for (int r = 0; r < ROWS; ++r) base[r] = alpha[row0 + r];
  float acc[ROWS][9];
#pragma unroll
  for (int r = 0; r < ROWS; ++r)
#pragma unroll
    for (int k = 0; k < 9; ++k) acc[r][k] = 0.0f;

  for (int jj = tid; jj < NJ4; jj += 256){
    const int j = jj*4;
    float f[ROWS][4];
#pragma unroll
    for (int r = 0; r < ROWS; ++r){
      const float* p = padded + base[r] + j;
#pragma unroll
      for (int e = 0; e < 4; ++e) f[r][e] = p[e];
    }
#pragma unroll
    for (int k = 0; k < 9; ++k){
      const float4 wv = *reinterpret_cast<const float4*>(w + k*FRLEN + j);
#pragma unroll
      for (int r = 0; r < ROWS; ++r){
        acc[r][k] = fmaf(f[r][0], wv.x, acc[r][k]);
        acc[r][k] = fmaf(f[r][1], wv.y, acc[r][k]);
        acc[r][k] = fmaf(f[r][2], wv.z, acc[r][k]);
        acc[r][k] = fmaf(f[r][3], wv.w, acc[r][k]);
      }
    }
  }
#pragma unroll
  for (int m = 32; m >= 1; m >>= 1){
#pragma unroll
    for (int r = 0; r < ROWS; ++r)
#pragma unroll
      for (int k = 0; k < 9; ++k)
        acc[r][k] += __shfl_xor(acc[r][k], m, 64);
  }
  __shared__ float red[4][36];
  const int wv_ = tid >> 6, ln = tid & 63;
  if (ln == 0){
#pragma unroll
    for (int r = 0; r < ROWS; ++r)
#pragma unroll
      for (int k = 0; k < 9; ++k) red[wv_][r*9+k] = acc[r][k];
  }
  __syncthreads();
  if (tid < 36){
    float s = red[0][tid] + red[1][tid] + red[2][tid] + red[3][tid];
    gi_out[row0*9 + tid] = s;
  }
}

__global__ void k_epi(const float* __restrict__ gi_in, const int* __restrict__ alpha,
    const float* __restrict__ gbih, const float* __restrict__ gbhh,
    const float* __restrict__ c2w, const float* __restrict__ c2b,
    const float* __restrict__ c3w, const float* __restrict__ c3b,
    const float* __restrict__ lw, const float* __restrict__ lb,
    const float* __restrict__ wih, const float* __restrict__ bih, const float* __restrict__ bhh,
    _Float16* __restrict__ pre){
  int t = blockIdx.x*blockDim.x + threadIdx.x;
  if (t >= TSTEPS) return;
  float gi[9];
#pragma unroll
  for (int k = 0; k < 9; ++k) gi[k] = gi_in[t*9+k] + gbih[k];
  float h[3];
#pragma unroll
  for (int q = 0; q < 3; ++q){
    float rr = sigmoidf_(gi[q]   + gbhh[q]);
    float zz = sigmoidf_(gi[3+q] + gbhh[3+q]);
    float nn = tanhf(gi[6+q] + rr*gbhh[6+q]);
    h[q] = (1.0f - zz)*nn;
  }
  float feat[16];
#pragma unroll
  for (int c = 0; c < 16; ++c) feat[c] = c3b[c];
  for (int ic = 0; ic < 32; ++ic){
    float w0 = c2w[ic*3+0], w1 = c2w[ic*3+1], w2 = c2w[ic*3+2], bb = c2b[ic];
    float x0 = fmaxf(bb + h[0]*w1 + h[1]*w2, 0.0f);
    float x1 = fmaxf(bb + h[0]*w0 + h[1]*w1 + h[2]*w2, 0.0f);
    float x2_ = fmaxf(bb + h[1]*w0 + h[2]*w1, 0.0f);
#pragma unroll
    for (int c = 0; c < 16; ++c){
      const float* wp = c3w + (c*32+ic)*3;
      feat[c] += x0*wp[0] + x1*wp[1] + x2_*wp[2];
    }
  }
  float interval = (float)(t == 0 ? alpha[0] : (alpha[t] - alpha[t-1]));
  float xin[10];
#pragma unroll
  for (int k = 0; k < 10; ++k){
    float s = lb[k] + interval*lw[k*17];
#pragma unroll
    for (int j = 0; j < 16; ++j) s = fmaf(feat[j], lw[k*17+1+j], s);
    xin[k] = s;
  }
  // LSTM input projection + both biases, fp16, layout pre[t*40 + gate*10 + unit]
  // scaled: i,f,o gates by -1; g gate by -2 (so act = rcp(1+exp(g')) forms)
#pragma unroll
  for (int k = 0; k < 40; ++k){
    float s = bih[k] + bhh[k];
#pragma unroll
    for (int i = 0; i < 10; ++i) s = fmaf(xin[i], wih[k*10+i], s);
    const float sc = (k >= 20 && k < 30) ? -2.0f : -1.0f;
    pre[t*40 + k] = (_Float16)(s * sc);
  }
}

// 1024 threads stage pre (fp16, 160KiB) into LDS; wave 0 runs the scan.
// Gate-per-lane: lane L = gate*10+unit (L<40). 10 FMAs + 1 act per step.
__global__ __launch_bounds__(1024, 1) void k_lstm(const _Float16* __restrict__ pre,
                       const float* __restrict__ whh,
                       const float* __restrict__ l1w, const float* __restrict__ l1b,
                       const float* __restrict__ l2w, const float* __restrict__ l2b,
                       float* __restrict__ out){
  extern __shared__ _Float16 sp[];   // sp[t*40 + L], pre-scaled
  {
    uint4* dst = (uint4*)sp;
    const uint4* src = (const uint4*)pre;
    for (int i = threadIdx.x; i < (TSTEPS*40*2)/16; i += 1024) dst[i] = src[i];
  }
  __syncthreads();
  if (threadIdx.x >= 64) return;

  const int lane = threadIdx.x;
  const int L = lane < 40 ? lane : 39;
  const bool is_g = (L >= 20 && L < 30);
  const float wsc = is_g ? -2.0f : -1.0f;
  const float s2  = is_g ?  2.0f : 1.0f;
  const float s3  = is_g ? -1.0f : 0.0f;
  float w[10];
#pragma unroll
  for (int i = 0; i < 10; ++i) w[i] = whh[L*10 + i] * wsc;

  float hs[10];
#pragma unroll
  for (int i = 0; i < 10; ++i) hs[i] = 0.0f;
  float c = 0.0f;
  const int i1 = (lane+10)&63, i2 = (lane+20)&63, i3 = (lane+30)&63;

  _Float16 q0 = sp[0*40+L], q1 = sp[1*40+L], q2 = sp[2*40+L], q3 = sp[3*40+L];
#pragma unroll 4
  for (int t = 0; t < TSTEPS; ++t){
    float g = (float)q0;
    q0 = q1; q1 = q2; q2 = q3;
    int tn = t + 4 < TSTEPS ? t + 4 : TSTEPS - 1;
    q3 = sp[tn*40 + L];
    float ga = g, gb = 0.0f;
#pragma unroll
    for (int i = 0; i < 5; ++i)  ga = fmaf(hs[i], w[i], ga);
#pragma unroll
    for (int i = 5; i < 10; ++i) gb = fmaf(hs[i], w[i], gb);
    g = ga + gb;
    float act = fmaf(__builtin_amdgcn_rcpf(1.0f + __expf(g)), s2, s3);
    float af = __shfl(act, i1, 64);
    float ag = __shfl(act, i2, 64);
    float ao = __shfl(act, i3, 64);
    c = fmaf(af, c, act*ag);                      // lanes 0..9: act = sigmoid(i)
    float th = fmaf(__builtin_amdgcn_rcpf(1.0f + __expf(-2.0f*c)), 2.0f, -1.0f);
    float hn = ao*th;
#pragma unroll
    for (int i = 0; i < 10; ++i)
      hs[i] = __int_as_float(__builtin_amdgcn_readlane(__float_as_int(hn), i));
  }
  float z = 0.0f;
  if (lane < 32){
    float s = l1b[lane];
#pragma unroll
    for (int i = 0; i < 10; ++i) s = fmaf(hs[i], l1w[lane*10+i], s);
    z = fmaxf(s, 0.0f) * l2w[lane];
  }
#pragma unroll
  for (int m = 32; m >= 1; m >>= 1) z += __shfl_xor(z, m, 64);
  if (lane == 0) out[0] = sigmoidf_(z + l2b[0]);
}

extern "C" void kernel_launch(void* const* d_in, const int* in_sizes, int n_in,
                              void* d_out, int out_size, void* d_ws, size_t ws_size,
                              hipStream_t stream){
  const float* sound     = (const float*)d_in[0];
  const int*   alpha     = (const int*)  d_in[1];
  const float* gru_w_ih  = (const float*)d_in[2];
  const float* gru_b_ih  = (const float*)d_in[3];
  const float* gru_b_hh  = (const float*)d_in[4];
  const float* conv2_w   = (const float*)d_in[5];
  const float* conv2_b   = (const float*)d_in[6];
  const float* conv3_w   = (const float*)d_in[7];
  const float* conv3_b   = (const float*)d_in[8];
  const float* lin_w     = (const float*)d_in[9];
  const float* lin_b     = (const float*)d_in[10];
  const float* lstm_w_ih = (const float*)d_in[11];
  const float* lstm_w_hh = (const float*)d_in[12];
  const float* lstm_b_ih = (const float*)d_in[13];
  const float* lstm_b_hh = (const float*)d_in[14];
  const float* lin1_w    = (const float*)d_in[15];
  const float* lin1_b    = (const float*)d_in[16];
  const float* lin2_w    = (const float*)d_in[17];
  const float* lin2_b    = (const float*)d_in[18];

  float* padded = (float*)d_ws;                    // PADLEN f32
  float* gi     = padded + PADLEN;                 // T*9 f32
  _Float16* pre = (_Float16*)(gi + TSTEPS*9);      // T*40 fp16 (16B-aligned)

  (void)hipFuncSetAttribute((const void*)k_lstm,
        hipFuncAttributeMaxDynamicSharedMemorySize, TSTEPS*40*2);

  hipLaunchKernelGGL(k_prep, dim3(2048), dim3(256), 0, stream, sound, padded);
  hipLaunchKernelGGL(k_gi, dim3(TSTEPS/ROWS), dim3(256), 0, stream, padded, alpha, gru_w_ih, gi);
  hipLaunchKernelGGL(k_epi, dim3(TSTEPS/256), dim3(256), 0, stream,
                     gi, alpha, gru_b_ih, gru_b_hh, conv2_w, conv2_b, conv3_w, conv3_b,
                     lin_w, lin_b, lstm_w_ih, lstm_b_ih, lstm_b_hh, pre);
  hipLaunchKernelGGL(k_lstm, dim3(1), dim3(1024), TSTEPS*40*2, stream,
                     pre, lstm_w_hh, lin1_w, lin1_b, lin2_w, lin2_b, (float*)d_out);
}

// Round 5
// 319.762 us; speedup vs baseline: 2.1989x; 1.0354x over previous
//
#include <hip/hip_runtime.h>

#define FRLEN 44100
#define FR2 22050
#define LSND 882000
#define PADLEN (LSND + FRLEN)   // 926100
#define TSTEPS 2048
#define ROWS 8
#define NJ4 (FRLEN/4)           // 11025
#define LOG2E 1.4426950408889634f

__device__ __forceinline__ float sigmoidf_(float x){ return 1.0f/(1.0f + __expf(-x)); }

__global__ void k_prep(const float* __restrict__ sound, float* __restrict__ padded){
  int stride = gridDim.x*blockDim.x;
  for (int i = blockIdx.x*blockDim.x + threadIdx.x; i < PADLEN; i += stride){
    int s = i - FR2;
    padded[i] = (s >= 0 && s < LSND) ? fabsf(sound[s]) : 0.0f;
  }
}

__global__ __launch_bounds__(256, 1) void k_gi(const float* __restrict__ padded,
                     const int* __restrict__ alpha,
                     const float* __restrict__ w,
                     float* __restrict__ gi_out){
  const int tid = threadIdx.x;
  const int row0 = blockIdx.x * ROWS;
  int base[ROWS];
#pragma unroll
  for (int r = 0; r < ROWS; ++r) base[r] = alpha[row0 + r];
  float acc[ROWS][9];
#pragma unroll
  for (int r = 0; r < ROWS; ++r)
#pragma unroll
    for (int k = 0; k < 9; ++k) acc[r][k] = 0.0f;

  for (int jj = tid; jj < NJ4; jj += 256){
    const int j = jj*4;
    float4 f[ROWS];
#pragma unroll
    for (int r = 0; r < ROWS; ++r)
      f[r] = *reinterpret_cast<const float4*>(padded + base[r] + j);
#pragma unroll
    for (int k = 0; k < 9; ++k){
      const float4 wv = *reinterpret_cast<const float4*>(w + k*FRLEN + j);
#pragma unroll
      for (int r = 0; r < ROWS; ++r){
        acc[r][k] = fmaf(f[r].x, wv.x, acc[r][k]);
        acc[r][k] = fmaf(f[r].y, wv.y, acc[r][k]);
        acc[r][k] = fmaf(f[r].z, wv.z, acc[r][k]);
        acc[r][k] = fmaf(f[r].w, wv.w, acc[r][k]);
      }
    }
  }
#pragma unroll
  for (int m = 32; m >= 1; m >>= 1){
#pragma unroll
    for (int r = 0; r < ROWS; ++r)
#pragma unroll
      for (int k = 0; k < 9; ++k)
        acc[r][k] += __shfl_xor(acc[r][k], m, 64);
  }
  __shared__ float red[4][ROWS*9];
  const int wv_ = tid >> 6, ln = tid & 63;
  if (ln == 0){
#pragma unroll
    for (int r = 0; r < ROWS; ++r)
#pragma unroll
      for (int k = 0; k < 9; ++k) red[wv_][r*9+k] = acc[r][k];
  }
  __syncthreads();
  if (tid < ROWS*9){
    float s = red[0][tid] + red[1][tid] + red[2][tid] + red[3][tid];
    gi_out[row0*9 + tid] = s;
  }
}

__global__ void k_epi(const float* __restrict__ gi_in, const int* __restrict__ alpha,
    const float* __restrict__ gbih, const float* __restrict__ gbhh,
    const float* __restrict__ c2w, const float* __restrict__ c2b,
    const float* __restrict__ c3w, const float* __restrict__ c3b,
    const float* __restrict__ lw, const float* __restrict__ lb,
    const float* __restrict__ wih, const float* __restrict__ bih, const float* __restrict__ bhh,
    _Float16* __restrict__ pre){
  int t = blockIdx.x*blockDim.x + threadIdx.x;
  if (t >= TSTEPS) return;
  float gi[9];
#pragma unroll
  for (int k = 0; k < 9; ++k) gi[k] = gi_in[t*9+k] + gbih[k];
  float h[3];
#pragma unroll
  for (int q = 0; q < 3; ++q){
    float rr = sigmoidf_(gi[q]   + gbhh[q]);
    float zz = sigmoidf_(gi[3+q] + gbhh[3+q]);
    float nn = tanhf(gi[6+q] + rr*gbhh[6+q]);
    h[q] = (1.0f - zz)*nn;
  }
  float feat[16];
#pragma unroll
  for (int c = 0; c < 16; ++c) feat[c] = c3b[c];
  for (int ic = 0; ic < 32; ++ic){
    float w0 = c2w[ic*3+0], w1 = c2w[ic*3+1], w2 = c2w[ic*3+2], bb = c2b[ic];
    float x0 = fmaxf(bb + h[0]*w1 + h[1]*w2, 0.0f);
    float x1 = fmaxf(bb + h[0]*w0 + h[1]*w1 + h[2]*w2, 0.0f);
    float x2_ = fmaxf(bb + h[1]*w0 + h[2]*w1, 0.0f);
#pragma unroll
    for (int c = 0; c < 16; ++c){
      const float* wp = c3w + (c*32+ic)*3;
      feat[c] += x0*wp[0] + x1*wp[1] + x2_*wp[2];
    }
  }
  float interval = (float)(t == 0 ? alpha[0] : (alpha[t] - alpha[t-1]));
  float xin[10];
#pragma unroll
  for (int k = 0; k < 10; ++k){
    float s = lb[k] + interval*lw[k*17];
#pragma unroll
    for (int j = 0; j < 16; ++j) s = fmaf(feat[j], lw[k*17+1+j], s);
    xin[k] = s;
  }
  // pre[t*40 + gate*10 + unit], pre-scaled so act = rcp(1+exp2(g'))-forms:
  // i,f,o: * -log2e ; g: * -2*log2e
#pragma unroll
  for (int k = 0; k < 40; ++k){
    float s = bih[k] + bhh[k];
#pragma unroll
    for (int i = 0; i < 10; ++i) s = fmaf(xin[i], wih[k*10+i], s);
    const float sc = (k >= 20 && k < 30) ? (-2.0f*LOG2E) : (-LOG2E);
    pre[t*40 + k] = (_Float16)(s * sc);
  }
}

// 1024 threads stage pre (fp16, 160KiB) into LDS; wave 0 runs the scan.
// Lane = 16*gate + unit. Cross-gate gather via v_permlane{16,32}_swap (VALU,
// ~4cy) instead of ds_bpermute (~120cy LDS round-trip).
__global__ __launch_bounds__(1024, 1) void k_lstm(const _Float16* __restrict__ pre,
                       const float* __restrict__ whh,
                       const float* __restrict__ l1w, const float* __restrict__ l1b,
                       const float* __restrict__ l2w, const float* __restrict__ l2b,
                       float* __restrict__ out){
  extern __shared__ _Float16 sp[];   // sp[t*40 + gate*10 + unit], pre-scaled
  {
    uint4* dst = (uint4*)sp;
    const uint4* src = (const uint4*)pre;
    for (int i = threadIdx.x; i < (TSTEPS*40*2)/16; i += 1024) dst[i] = src[i];
  }
  __syncthreads();
  if (threadIdx.x >= 64) return;

  const int lane = threadIdx.x;
  const int gate = lane >> 4;
  const int unit_raw = lane & 15;
  const int unit = unit_raw < 10 ? unit_raw : 9;
  const int L40 = gate*10 + unit;              // row in whh / index in sp step
  const bool is_g = (gate == 2);
  const float wsc = is_g ? (-2.0f*LOG2E) : (-LOG2E);
  const float s2  = is_g ?  2.0f : 1.0f;
  const float s3  = is_g ? -1.0f : 0.0f;
  float w[10];
#pragma unroll
  for (int i = 0; i < 10; ++i) w[i] = whh[L40*10 + i] * wsc;

  float hs[10];
#pragma unroll
  for (int i = 0; i < 10; ++i) hs[i] = 0.0f;
  float c = 0.0f;

  _Float16 q0 = sp[0*40+L40], q1 = sp[1*40+L40], q2 = sp[2*40+L40], q3 = sp[3*40+L40];
#pragma unroll 4
  for (int t = 0; t < TSTEPS; ++t){
    float cv = (float)q0;
    q0 = q1; q1 = q2; q2 = q3;
    int tn = t + 4 < TSTEPS ? t + 4 : TSTEPS - 1;
    q3 = sp[tn*40 + L40];
    float ga = cv, gb = 0.0f;
#pragma unroll
    for (int i = 0; i < 5; ++i)  ga = fmaf(hs[i], w[i], ga);
#pragma unroll
    for (int i = 5; i < 10; ++i) gb = fmaf(hs[i], w[i], gb);
    float g = ga + gb;
    // act: sigmoid for i,f,o ; tanh for g (folded scales)
    float act = fmaf(__builtin_amdgcn_rcpf(1.0f + __builtin_amdgcn_exp2f(g)), s2, s3);
    // gather: lane u (<10) wants f=act[16+u], g=act[32+u], o=act[48+u]
    float d1 = act, g_sw = act;   // 32-swap: g_sw[u] = act[32+u]
    asm("s_nop 1\n\tv_permlane32_swap_b32 %0, %1" : "+v"(d1), "+v"(g_sw));
    float d2 = act, f_sw = act;   // 16-swap: f_sw[u] = act[16+u]
    asm("v_permlane16_swap_b32 %0, %1" : "+v"(d2), "+v"(f_sw));
    float d3 = g_sw, o_sw = g_sw; // 16-swap of g_sw: o_sw[u] = act[48+u]
    asm("s_nop 1\n\tv_permlane16_swap_b32 %0, %1" : "+v"(d3), "+v"(o_sw));
    // lanes 0..9: act = sigmoid(i)
    float ig = act * g_sw;
    c = fmaf(f_sw, c, ig);
    float th = fmaf(__builtin_amdgcn_rcpf(1.0f + __builtin_amdgcn_exp2f(c * (-2.0f*LOG2E))), 2.0f, -1.0f);
    float hn = o_sw * th;
#pragma unroll
    for (int i = 0; i < 10; ++i)
      hs[i] = __int_as_float(__builtin_amdgcn_readlane(__float_as_int(hn), i));
  }
  float z = 0.0f;
  if (lane < 32){
    float s = l1b[lane];
#pragma unroll
    for (int i = 0; i < 10; ++i) s = fmaf(hs[i], l1w[lane*10+i], s);
    z = fmaxf(s, 0.0f) * l2w[lane];
  }
#pragma unroll
  for (int m = 32; m >= 1; m >>= 1) z += __shfl_xor(z, m, 64);
  if (lane == 0) out[0] = sigmoidf_(z + l2b[0]);
}

extern "C" void kernel_launch(void* const* d_in, const int* in_sizes, int n_in,
                              void* d_out, int out_size, void* d_ws, size_t ws_size,
                              hipStream_t stream){
  const float* sound     = (const float*)d_in[0];
  const int*   alpha     = (const int*)  d_in[1];
  const float* gru_w_ih  = (const float*)d_in[2];
  const float* gru_b_ih  = (const float*)d_in[3];
  const float* gru_b_hh  = (const float*)d_in[4];
  const float* conv2_w   = (const float*)d_in[5];
  const float* conv2_b   = (const float*)d_in[6];
  const float* conv3_w   = (const float*)d_in[7];
  const float* conv3_b   = (const float*)d_in[8];
  const float* lin_w     = (const float*)d_in[9];
  const float* lin_b     = (const float*)d_in[10];
  const float* lstm_w_ih = (const float*)d_in[11];
  const float* lstm_w_hh = (const float*)d_in[12];
  const float* lstm_b_ih = (const float*)d_in[13];
  const float* lstm_b_hh = (const float*)d_in[14];
  const float* lin1_w    = (const float*)d_in[15];
  const float* lin1_b    = (const float*)d_in[16];
  const float* lin2_w    = (const float*)d_in[17];
  const float* lin2_b    = (const float*)d_in[18];

  float* padded = (float*)d_ws;                    // PADLEN f32
  float* gi     = padded + PADLEN;                 // T*9 f32
  _Float16* pre = (_Float16*)(gi + TSTEPS*9);      // T*40 fp16 (16B-aligned)

  (void)hipFuncSetAttribute((const void*)k_lstm,
        hipFuncAttributeMaxDynamicSharedMemorySize, TSTEPS*40*2);

  hipLaunchKernelGGL(k_prep, dim3(2048), dim3(256), 0, stream, sound, padded);
  hipLaunchKernelGGL(k_gi, dim3(TSTEPS/ROWS), dim3(256), 0, stream, padded, alpha, gru_w_ih, gi);
  hipLaunchKernelGGL(k_epi, dim3(TSTEPS/256), dim3(256), 0, stream,
                     gi, alpha, gru_b_ih, gru_b_hh, conv2_w, conv2_b, conv3_w, conv3_b,
                     lin_w, lin_b, lstm_w_ih, lstm_b_ih, lstm_b_hh, pre);
  hipLaunchKernelGGL(k_lstm, dim3(1), dim3(1024), TSTEPS*40*2, stream,
                     pre, lstm_w_hh, lin1_w, lin1_b, lin2_w, lin2_b, (float*)d_out);
}

// Round 6
// 276.641 us; speedup vs baseline: 2.5417x; 1.1559x over previous
//
#include <hip/hip_runtime.h>

#define FRLEN 44100
#define FR2 22050
#define LSND 882000
#define PADLEN (LSND + FRLEN)   // 926100
#define TSTEPS 2048
#define ROWS 8
#define NJ4 (FRLEN/4)           // 11025
#define LOG2E 1.4426950408889634f

__device__ __forceinline__ float sigmoidf_(float x){ return 1.0f/(1.0f + __expf(-x)); }

__global__ void k_prep(const float* __restrict__ sound, float* __restrict__ padded){
  int stride = gridDim.x*blockDim.x;
  for (int i = blockIdx.x*blockDim.x + threadIdx.x; i < PADLEN; i += stride){
    int s = i - FR2;
    padded[i] = (s >= 0 && s < LSND) ? fabsf(sound[s]) : 0.0f;
  }
}

// 512 threads (8 waves = 2/SIMD for latency hiding), 8 rows/block.
__global__ __launch_bounds__(512, 2) void k_gi(const float* __restrict__ padded,
                     const int* __restrict__ alpha,
                     const float* __restrict__ w,
                     float* __restrict__ gi_out){
  const int tid = threadIdx.x;
  const int row0 = blockIdx.x * ROWS;
  int base[ROWS];
#pragma unroll
  for (int r = 0; r < ROWS; ++r) base[r] = alpha[row0 + r];
  float acc[ROWS][9];
#pragma unroll
  for (int r = 0; r < ROWS; ++r)
#pragma unroll
    for (int k = 0; k < 9; ++k) acc[r][k] = 0.0f;

  for (int jj = tid; jj < NJ4; jj += 512){
    const int j = jj*4;
    float4 f[ROWS];
#pragma unroll
    for (int r = 0; r < ROWS; ++r)
      f[r] = *reinterpret_cast<const float4*>(padded + base[r] + j);
#pragma unroll
    for (int k = 0; k < 9; ++k){
      const float4 wv = *reinterpret_cast<const float4*>(w + k*FRLEN + j);
#pragma unroll
      for (int r = 0; r < ROWS; ++r){
        acc[r][k] = fmaf(f[r].x, wv.x, acc[r][k]);
        acc[r][k] = fmaf(f[r].y, wv.y, acc[r][k]);
        acc[r][k] = fmaf(f[r].z, wv.z, acc[r][k]);
        acc[r][k] = fmaf(f[r].w, wv.w, acc[r][k]);
      }
    }
  }
#pragma unroll
  for (int m = 32; m >= 1; m >>= 1){
#pragma unroll
    for (int r = 0; r < ROWS; ++r)
#pragma unroll
      for (int k = 0; k < 9; ++k)
        acc[r][k] += __shfl_xor(acc[r][k], m, 64);
  }
  __shared__ float red[8][ROWS*9];
  const int wv_ = tid >> 6, ln = tid & 63;
  if (ln == 0){
#pragma unroll
    for (int r = 0; r < ROWS; ++r)
#pragma unroll
      for (int k = 0; k < 9; ++k) red[wv_][r*9+k] = acc[r][k];
  }
  __syncthreads();
  if (tid < ROWS*9){
    float s = 0.0f;
#pragma unroll
    for (int q = 0; q < 8; ++q) s += red[q][tid];
    gi_out[row0*9 + tid] = s;
  }
}

__global__ void k_epi(const float* __restrict__ gi_in, const int* __restrict__ alpha,
    const float* __restrict__ gbih, const float* __restrict__ gbhh,
    const float* __restrict__ c2w, const float* __restrict__ c2b,
    const float* __restrict__ c3w, const float* __restrict__ c3b,
    const float* __restrict__ lw, const float* __restrict__ lb,
    const float* __restrict__ wih, const float* __restrict__ bih, const float* __restrict__ bhh,
    _Float16* __restrict__ pre){
  int t = blockIdx.x*blockDim.x + threadIdx.x;
  if (t >= TSTEPS) return;
  float gi[9];
#pragma unroll
  for (int k = 0; k < 9; ++k) gi[k] = gi_in[t*9+k] + gbih[k];
  float h[3];
#pragma unroll
  for (int q = 0; q < 3; ++q){
    float rr = sigmoidf_(gi[q]   + gbhh[q]);
    float zz = sigmoidf_(gi[3+q] + gbhh[3+q]);
    float nn = tanhf(gi[6+q] + rr*gbhh[6+q]);
    h[q] = (1.0f - zz)*nn;
  }
  float feat[16];
#pragma unroll
  for (int c = 0; c < 16; ++c) feat[c] = c3b[c];
  for (int ic = 0; ic < 32; ++ic){
    float w0 = c2w[ic*3+0], w1 = c2w[ic*3+1], w2 = c2w[ic*3+2], bb = c2b[ic];
    float x0 = fmaxf(bb + h[0]*w1 + h[1]*w2, 0.0f);
    float x1 = fmaxf(bb + h[0]*w0 + h[1]*w1 + h[2]*w2, 0.0f);
    float x2_ = fmaxf(bb + h[1]*w0 + h[2]*w1, 0.0f);
#pragma unroll
    for (int c = 0; c < 16; ++c){
      const float* wp = c3w + (c*32+ic)*3;
      feat[c] += x0*wp[0] + x1*wp[1] + x2_*wp[2];
    }
  }
  float interval = (float)(t == 0 ? alpha[0] : (alpha[t] - alpha[t-1]));
  float xin[10];
#pragma unroll
  for (int k = 0; k < 10; ++k){
    float s = lb[k] + interval*lw[k*17];
#pragma unroll
    for (int j = 0; j < 16; ++j) s = fmaf(feat[j], lw[k*17+1+j], s);
    xin[k] = s;
  }
  // pre[t*40 + gate*10 + unit], pre-scaled: i,f,o by -log2e ; g by -2*log2e
#pragma unroll
  for (int k = 0; k < 40; ++k){
    float s = bih[k] + bhh[k];
#pragma unroll
    for (int i = 0; i < 10; ++i) s = fmaf(xin[i], wih[k*10+i], s);
    const float sc = (k >= 20 && k < 30) ? (-2.0f*LOG2E) : (-LOG2E);
    pre[t*40 + k] = (_Float16)(s * sc);
  }
}

// One LSTM step. act's row 0 (i-gate, lanes 0..9) survives all swaps, so it
// doubles as the mutable permlane destination (saves v_movs).
#define LSTM_STEP(PREFETCH_STMT)                                              \
  {                                                                           \
    float g = (float)q0;                                                      \
    q0 = q1; q1 = q2; q2 = q3;                                                \
    PREFETCH_STMT;                                                            \
    float ga = g, gb = 0.0f;                                                  \
    _Pragma("unroll")                                                         \
    for (int i = 0; i < 5; ++i)  ga = fmaf(hs[i], w[i], ga);                  \
    _Pragma("unroll")                                                         \
    for (int i = 5; i < 10; ++i) gb = fmaf(hs[i], w[i], gb);                  \
    g = ga + gb;                                                              \
    float act = fmaf(__builtin_amdgcn_rcpf(1.0f + __builtin_amdgcn_exp2f(g)), s2, s3); \
    float g_sw = act;                                                         \
    asm("s_nop 1\n\tv_permlane32_swap_b32 %0, %1" : "+v"(act), "+v"(g_sw));   \
    float f_sw = act;                                                         \
    asm("v_permlane16_swap_b32 %0, %1" : "+v"(act), "+v"(f_sw));              \
    float o_sw = g_sw;                                                        \
    asm("v_permlane16_swap_b32 %0, %1" : "+v"(g_sw), "+v"(o_sw));             \
    float ig = act * g_sw;            /* lanes 0..9: sigmoid(i) * k*tanh(g) */\
    c = fmaf(f_sw, c, ig);            /* c is k-scaled cell state */          \
    float th = fmaf(__builtin_amdgcn_rcpf(1.0f + __builtin_amdgcn_exp2f(c)), 2.0f, -1.0f); \
    float hn = o_sw * th;                                                     \
    _Pragma("unroll")                                                         \
    for (int i = 0; i < 10; ++i)                                              \
      hs[i] = __int_as_float(__builtin_amdgcn_readlane(__float_as_int(hn), i)); \
  }

// 1024 threads stage pre (fp16, 160KiB) into LDS; wave 0 runs the scan.
// Lane = 16*gate + unit; cross-gate gather via v_permlane{16,32}_swap.
__global__ __launch_bounds__(1024, 1) void k_lstm(const _Float16* __restrict__ pre,
                       const float* __restrict__ whh,
                       const float* __restrict__ l1w, const float* __restrict__ l1b,
                       const float* __restrict__ l2w, const float* __restrict__ l2b,
                       float* __restrict__ out){
  extern __shared__ _Float16 sp[];   // sp[t*40 + gate*10 + unit], pre-scaled
  {
    uint4* dst = (uint4*)sp;
    const uint4* src = (const uint4*)pre;
    for (int i = threadIdx.x; i < (TSTEPS*40*2)/16; i += 1024) dst[i] = src[i];
  }
  __syncthreads();
  if (threadIdx.x >= 64) return;

  const int lane = threadIdx.x;
  const int gate = lane >> 4;
  const int unit_raw = lane & 15;
  const int unit = unit_raw < 10 ? unit_raw : 9;
  const int L40 = gate*10 + unit;
  const bool is_g = (gate == 2);
  const float kk  = -2.0f*LOG2E;               // cell-state scale
  const float wsc = is_g ? kk : (-LOG2E);
  const float s2  = is_g ? (2.0f*kk) : 1.0f;   // g-act returns k*tanh
  const float s3  = is_g ? (-kk)     : 0.0f;
  float w[10];
#pragma unroll
  for (int i = 0; i < 10; ++i) w[i] = whh[L40*10 + i] * wsc;

  float hs[10];
#pragma unroll
  for (int i = 0; i < 10; ++i) hs[i] = 0.0f;
  float c = 0.0f;   // k-scaled cell

  _Float16 q0 = sp[0*40+L40], q1 = sp[1*40+L40], q2 = sp[2*40+L40], q3 = sp[3*40+L40];
#pragma unroll 4
  for (int t = 0; t < TSTEPS-4; ++t){
    LSTM_STEP(q3 = sp[(t+4)*40 + L40]);
  }
#pragma unroll
  for (int t = TSTEPS-4; t < TSTEPS; ++t){
    LSTM_STEP(;);
  }
  float z = 0.0f;
  if (lane < 32){
    float s = l1b[lane];
#pragma unroll
    for (int i = 0; i < 10; ++i) s = fmaf(hs[i], l1w[lane*10+i], s);
    z = fmaxf(s, 0.0f) * l2w[lane];
  }
#pragma unroll
  for (int m = 32; m >= 1; m >>= 1) z += __shfl_xor(z, m, 64);
  if (lane == 0) out[0] = sigmoidf_(z + l2b[0]);
}

extern "C" void kernel_launch(void* const* d_in, const int* in_sizes, int n_in,
                              void* d_out, int out_size, void* d_ws, size_t ws_size,
                              hipStream_t stream){
  const float* sound     = (const float*)d_in[0];
  const int*   alpha     = (const int*)  d_in[1];
  const float* gru_w_ih  = (const float*)d_in[2];
  const float* gru_b_ih  = (const float*)d_in[3];
  const float* gru_b_hh  = (const float*)d_in[4];
  const float* conv2_w   = (const float*)d_in[5];
  const float* conv2_b   = (const float*)d_in[6];
  const float* conv3_w   = (const float*)d_in[7];
  const float* conv3_b   = (const float*)d_in[8];
  const float* lin_w     = (const float*)d_in[9];
  const float* lin_b     = (const float*)d_in[10];
  const float* lstm_w_ih = (const float*)d_in[11];
  const float* lstm_w_hh = (const float*)d_in[12];
  const float* lstm_b_ih = (const float*)d_in[13];
  const float* lstm_b_hh = (const float*)d_in[14];
  const float* lin1_w    = (const float*)d_in[15];
  const float* lin1_b    = (const float*)d_in[16];
  const float* lin2_w    = (const float*)d_in[17];
  const float* lin2_b    = (const float*)d_in[18];

  float* padded = (float*)d_ws;                    // PADLEN f32
  float* gi     = padded + PADLEN;                 // T*9 f32
  _Float16* pre = (_Float16*)(gi + TSTEPS*9);      // T*40 fp16 (16B-aligned)

  (void)hipFuncSetAttribute((const void*)k_lstm,
        hipFuncAttributeMaxDynamicSharedMemorySize, TSTEPS*40*2);

  hipLaunchKernelGGL(k_prep, dim3(2048), dim3(256), 0, stream, sound, padded);
  hipLaunchKernelGGL(k_gi, dim3(TSTEPS/ROWS), dim3(512), 0, stream, padded, alpha, gru_w_ih, gi);
  hipLaunchKernelGGL(k_epi, dim3(TSTEPS/256), dim3(256), 0, stream,
                     gi, alpha, gru_b_ih, gru_b_hh, conv2_w, conv2_b, conv3_w, conv3_b,
                     lin_w, lin_b, lstm_w_ih, lstm_b_ih, lstm_b_hh, pre);
  hipLaunchKernelGGL(k_lstm, dim3(1), dim3(1024), TSTEPS*40*2, stream,
                     pre, lstm_w_hh, lin1_w, lin1_b, lin2_w, lin2_b, (float*)d_out);
}

// Round 7
// 260.773 us; speedup vs baseline: 2.6964x; 1.0608x over previous
//
#include <hip/hip_runtime.h>

#define FRLEN 44100
#define FR2 22050
#define LSND 882000
#define PADLEN (LSND + FRLEN)   // 926100
#define TSTEPS 2048
#define ROWS 8
#define LOG2E 1.4426950408889634f

#define KPAD 44104              // K rounded up to 8
#define WPROW (KPAD/2)          // 22052 pairs per weight row
#define NJP (WPROW/4)           // 5513 quad-pair iterations
#define PAIRS 463056            // half2 pairs in pA/pB (covers PADLEN+slack)

typedef _Float16 half2_ __attribute__((ext_vector_type(2)));

__device__ __forceinline__ float sigmoidf_(float x){ return 1.0f/(1.0f + __expf(-x)); }

__device__ __forceinline__ float dot2_(uint a, uint b, float c){
#if __has_builtin(__builtin_amdgcn_fdot2)
  return __builtin_amdgcn_fdot2(*(half2_*)&a, *(half2_*)&b, c, false);
#else
  half2_ ha = *(half2_*)&a, hb = *(half2_*)&b;
  c = fmaf((float)ha.x, (float)hb.x, c);
  return fmaf((float)ha.y, (float)hb.y, c);
#endif
}

// Build |sound| fp16 pair arrays (even-start pA, odd-start pB) + fp16 weight pairs.
__global__ void k_prep16(const float* __restrict__ sound, const float* __restrict__ w,
                         uint* __restrict__ pA, uint* __restrict__ pB,
                         uint* __restrict__ wp){
  const int stride = gridDim.x*blockDim.x;
  for (int i = blockIdx.x*blockDim.x + threadIdx.x; i < PAIRS + 9*WPROW; i += stride){
    if (i < PAIRS){
      int e0 = 2*i - FR2;          // element indices in padded space, minus FR2
      float v0 = (e0 >= 0     && e0 < LSND)     ? fabsf(sound[e0])   : 0.0f;
      float v1 = (e0+1 >= 0   && e0+1 < LSND)   ? fabsf(sound[e0+1]) : 0.0f;
      float v2 = (e0+2 >= 0   && e0+2 < LSND)   ? fabsf(sound[e0+2]) : 0.0f;
      half2_ a = { (_Float16)v0, (_Float16)v1 };
      half2_ b = { (_Float16)v1, (_Float16)v2 };
      pA[i] = *(uint*)&a;
      pB[i] = *(uint*)&b;
    } else {
      int p = i - PAIRS;           // wp linear index: k*WPROW + pair
      int k = p / WPROW, pr = p % WPROW;
      int j = 2*pr;
      float v0 = (j   < FRLEN) ? w[k*FRLEN + j]   : 0.0f;
      float v1 = (j+1 < FRLEN) ? w[k*FRLEN + j+1] : 0.0f;
      half2_ a = { (_Float16)v0, (_Float16)v1 };
      wp[i - PAIRS] = *(uint*)&a;
    }
  }
}

// Fused: gi matmul (fp16 dot2, fp32 acc) + GRU pointwise + convs + linear +
// LSTM input projection -> pre (fp16, pre-scaled). 8 rows/block, 512 threads.
__global__ __launch_bounds__(512, 2) void k_front(const uint* __restrict__ pA,
    const uint* __restrict__ pB, const uint* __restrict__ wp,
    const int* __restrict__ alpha,
    const float* __restrict__ gbih, const float* __restrict__ gbhh,
    const float* __restrict__ c2w, const float* __restrict__ c2b,
    const float* __restrict__ c3w, const float* __restrict__ c3b,
    const float* __restrict__ lw, const float* __restrict__ lb,
    const float* __restrict__ wih, const float* __restrict__ bih, const float* __restrict__ bhh,
    _Float16* __restrict__ pre){
  const int tid = threadIdx.x;
  const int row0 = blockIdx.x * ROWS;
  const uint* hp[ROWS];
  int idx0[ROWS];
#pragma unroll
  for (int r = 0; r < ROWS; ++r){
    int b = alpha[row0 + r];
    hp[r] = (b & 1) ? pB : pA;
    idx0[r] = b >> 1;
  }
  float acc[ROWS][9];
#pragma unroll
  for (int r = 0; r < ROWS; ++r)
#pragma unroll
    for (int k = 0; k < 9; ++k) acc[r][k] = 0.0f;

  for (int jj = tid; jj < NJP; jj += 512){
    const int jp = jj*4;
    uint4 f[ROWS];
#pragma unroll
    for (int r = 0; r < ROWS; ++r){
      const uint* p = hp[r] + idx0[r] + jp;
      f[r].x = p[0]; f[r].y = p[1]; f[r].z = p[2]; f[r].w = p[3];
    }
#pragma unroll
    for (int k = 0; k < 9; ++k){
      const uint4 wq = *reinterpret_cast<const uint4*>(wp + k*WPROW + jp);
#pragma unroll
      for (int r = 0; r < ROWS; ++r){
        acc[r][k] = dot2_(f[r].x, wq.x, acc[r][k]);
        acc[r][k] = dot2_(f[r].y, wq.y, acc[r][k]);
        acc[r][k] = dot2_(f[r].z, wq.z, acc[r][k]);
        acc[r][k] = dot2_(f[r].w, wq.w, acc[r][k]);
      }
    }
  }
#pragma unroll
  for (int m = 32; m >= 1; m >>= 1){
#pragma unroll
    for (int r = 0; r < ROWS; ++r)
#pragma unroll
      for (int k = 0; k < 9; ++k)
        acc[r][k] += __shfl_xor(acc[r][k], m, 64);
  }
  __shared__ float red[8][ROWS*9];
  __shared__ float sgi[ROWS*9];
  const int wv_ = tid >> 6, ln = tid & 63;
  if (ln == 0){
#pragma unroll
    for (int r = 0; r < ROWS; ++r)
#pragma unroll
      for (int k = 0; k < 9; ++k) red[wv_][r*9+k] = acc[r][k];
  }
  __syncthreads();
  if (tid < ROWS*9){
    float s = 0.0f;
#pragma unroll
    for (int q = 0; q < 8; ++q) s += red[q][tid];
    sgi[tid] = s;
  }
  __syncthreads();
  if (tid < ROWS){
    const int t = row0 + tid;
    float gi[9];
#pragma unroll
    for (int k = 0; k < 9; ++k) gi[k] = sgi[tid*9+k] + gbih[k];
    float h[3];
#pragma unroll
    for (int q = 0; q < 3; ++q){
      float rr = sigmoidf_(gi[q]   + gbhh[q]);
      float zz = sigmoidf_(gi[3+q] + gbhh[3+q]);
      float nn = tanhf(gi[6+q] + rr*gbhh[6+q]);
      h[q] = (1.0f - zz)*nn;
    }
    float feat[16];
#pragma unroll
    for (int c = 0; c < 16; ++c) feat[c] = c3b[c];
    for (int ic = 0; ic < 32; ++ic){
      float w0 = c2w[ic*3+0], w1 = c2w[ic*3+1], w2 = c2w[ic*3+2], bb = c2b[ic];
      float x0 = fmaxf(bb + h[0]*w1 + h[1]*w2, 0.0f);
      float x1 = fmaxf(bb + h[0]*w0 + h[1]*w1 + h[2]*w2, 0.0f);
      float x2_ = fmaxf(bb + h[1]*w0 + h[2]*w1, 0.0f);
#pragma unroll
      for (int c = 0; c < 16; ++c){
        const float* wpp = c3w + (c*32+ic)*3;
        feat[c] += x0*wpp[0] + x1*wpp[1] + x2_*wpp[2];
      }
    }
    float interval = (float)(t == 0 ? alpha[0] : (alpha[t] - alpha[t-1]));
    float xin[10];
#pragma unroll
    for (int k = 0; k < 10; ++k){
      float s = lb[k] + interval*lw[k*17];
#pragma unroll
      for (int j = 0; j < 16; ++j) s = fmaf(feat[j], lw[k*17+1+j], s);
      xin[k] = s;
    }
    // pre[t*40 + gate*10 + unit], pre-scaled: i,f,o by -log2e ; g by -2*log2e
#pragma unroll
    for (int k = 0; k < 40; ++k){
      float s = bih[k] + bhh[k];
#pragma unroll
      for (int i = 0; i < 10; ++i) s = fmaf(xin[i], wih[k*10+i], s);
      const float sc = (k >= 20 && k < 30) ? (-2.0f*LOG2E) : (-LOG2E);
      pre[t*40 + k] = (_Float16)(s * sc);
    }
  }
}

// One LSTM step; act's row 0 (i-gate) survives all swaps.
#define LSTM_STEP(PREFETCH_STMT)                                              \
  {                                                                           \
    float g = (float)q0;                                                      \
    q0 = q1; q1 = q2; q2 = q3;                                                \
    PREFETCH_STMT;                                                            \
    float ga = g, gb = 0.0f;                                                  \
    _Pragma("unroll")                                                         \
    for (int i = 0; i < 5; ++i)  ga = fmaf(hs[i], w[i], ga);                  \
    _Pragma("unroll")                                                         \
    for (int i = 5; i < 10; ++i) gb = fmaf(hs[i], w[i], gb);                  \
    g = ga + gb;                                                              \
    float act = fmaf(__builtin_amdgcn_rcpf(1.0f + __builtin_amdgcn_exp2f(g)), s2, s3); \
    float g_sw = act;                                                         \
    asm("s_nop 0\n\tv_permlane32_swap_b32 %0, %1" : "+v"(act), "+v"(g_sw));   \
    float f_sw = act;                                                         \
    asm("v_permlane16_swap_b32 %0, %1" : "+v"(act), "+v"(f_sw));              \
    float o_sw = g_sw;                                                        \
    asm("s_nop 0\n\tv_permlane16_swap_b32 %0, %1" : "+v"(g_sw), "+v"(o_sw));  \
    float ig = act * g_sw;                                                    \
    c = fmaf(f_sw, c, ig);                                                    \
    float th = fmaf(__builtin_amdgcn_rcpf(1.0f + __builtin_amdgcn_exp2f(c)), 2.0f, -1.0f); \
    float hn = o_sw * th;                                                     \
    _Pragma("unroll")                                                         \
    for (int i = 0; i < 10; ++i)                                              \
      hs[i] = __int_as_float(__builtin_amdgcn_readlane(__float_as_int(hn), i)); \
  }

__global__ __launch_bounds__(1024, 1) void k_lstm(const _Float16* __restrict__ pre,
                       const float* __restrict__ whh,
                       const float* __restrict__ l1w, const float* __restrict__ l1b,
                       const float* __restrict__ l2w, const float* __restrict__ l2b,
                       float* __restrict__ out){
  extern __shared__ _Float16 sp[];   // sp[t*40 + gate*10 + unit], pre-scaled
  {
    uint4* dst = (uint4*)sp;
    const uint4* src = (const uint4*)pre;
    for (int i = threadIdx.x; i < (TSTEPS*40*2)/16; i += 1024) dst[i] = src[i];
  }
  __syncthreads();
  if (threadIdx.x >= 64) return;

  const int lane = threadIdx.x;
  const int gate = lane >> 4;
  const int unit_raw = lane & 15;
  const int unit = unit_raw < 10 ? unit_raw : 9;
  const int L40 = gate*10 + unit;
  const bool is_g = (gate == 2);
  const float kk  = -2.0f*LOG2E;
  const float wsc = is_g ? kk : (-LOG2E);
  const float s2  = is_g ? (2.0f*kk) : 1.0f;
  const float s3  = is_g ? (-kk)     : 0.0f;
  float w[10];
#pragma unroll
  for (int i = 0; i < 10; ++i) w[i] = whh[L40*10 + i] * wsc;

  float hs[10];
#pragma unroll
  for (int i = 0; i < 10; ++i) hs[i] = 0.0f;
  float c = 0.0f;

  _Float16 q0 = sp[0*40+L40], q1 = sp[1*40+L40], q2 = sp[2*40+L40], q3 = sp[3*40+L40];
#pragma unroll 4
  for (int t = 0; t < TSTEPS-4; ++t){
    LSTM_STEP(q3 = sp[(t+4)*40 + L40]);
  }
#pragma unroll
  for (int t = TSTEPS-4; t < TSTEPS; ++t){
    LSTM_STEP(;);
  }
  float z = 0.0f;
  if (lane < 32){
    float s = l1b[lane];
#pragma unroll
    for (int i = 0; i < 10; ++i) s = fmaf(hs[i], l1w[lane*10+i], s);
    z = fmaxf(s, 0.0f) * l2w[lane];
  }
#pragma unroll
  for (int m = 32; m >= 1; m >>= 1) z += __shfl_xor(z, m, 64);
  if (lane == 0) out[0] = sigmoidf_(z + l2b[0]);
}

extern "C" void kernel_launch(void* const* d_in, const int* in_sizes, int n_in,
                              void* d_out, int out_size, void* d_ws, size_t ws_size,
                              hipStream_t stream){
  const float* sound     = (const float*)d_in[0];
  const int*   alpha     = (const int*)  d_in[1];
  const float* gru_w_ih  = (const float*)d_in[2];
  const float* gru_b_ih  = (const float*)d_in[3];
  const float* gru_b_hh  = (const float*)d_in[4];
  const float* conv2_w   = (const float*)d_in[5];
  const float* conv2_b   = (const float*)d_in[6];
  const float* conv3_w   = (const float*)d_in[7];
  const float* conv3_b   = (const float*)d_in[8];
  const float* lin_w     = (const float*)d_in[9];
  const float* lin_b     = (const float*)d_in[10];
  const float* lstm_w_ih = (const float*)d_in[11];
  const float* lstm_w_hh = (const float*)d_in[12];
  const float* lstm_b_ih = (const float*)d_in[13];
  const float* lstm_b_hh = (const float*)d_in[14];
  const float* lin1_w    = (const float*)d_in[15];
  const float* lin1_b    = (const float*)d_in[16];
  const float* lin2_w    = (const float*)d_in[17];
  const float* lin2_b    = (const float*)d_in[18];

  char* ws = (char*)d_ws;
  uint* pA      = (uint*)ws;                         // PAIRS uints (1.85 MB)
  uint* pB      = pA + PAIRS;                        // PAIRS uints
  uint* wpairs  = pB + PAIRS;                        // 9*WPROW uints (0.79 MB)
  _Float16* pre = (_Float16*)(wpairs + 9*WPROW);     // T*40 fp16 (160 KB)

  (void)hipFuncSetAttribute((const void*)k_lstm,
        hipFuncAttributeMaxDynamicSharedMemorySize, TSTEPS*40*2);

  hipLaunchKernelGGL(k_prep16, dim3(1536), dim3(256), 0, stream,
                     sound, gru_w_ih, pA, pB, wpairs);
  hipLaunchKernelGGL(k_front, dim3(TSTEPS/ROWS), dim3(512), 0, stream,
                     pA, pB, wpairs, alpha,
                     gru_b_ih, gru_b_hh, conv2_w, conv2_b, conv3_w, conv3_b,
                     lin_w, lin_b, lstm_w_ih, lstm_b_ih, lstm_b_hh, pre);
  hipLaunchKernelGGL(k_lstm, dim3(1), dim3(1024), TSTEPS*40*2, stream,
                     pre, lstm_w_hh, lin1_w, lin1_b, lin2_w, lin2_b, (float*)d_out);
}

// Round 9
// 247.164 us; speedup vs baseline: 2.8448x; 1.0551x over previous
//
#include <hip/hip_runtime.h>

#define FRLEN 44100
#define FR2 22050
#define LSND 882000
#define PADLEN (LSND + FRLEN)   // 926100
#define TSTEPS 2048
#define ROWS 8
#define LOG2E 1.4426950408889634f

#define KPAD 44104              // K rounded up to 8
#define WPROW (KPAD/2)          // 22052 pairs per weight row
#define NJP (WPROW/4)           // 5513 quad-pair iterations
#define PAIRS 463056            // half2 pairs in pA/pB (covers PADLEN+slack)

typedef _Float16 half2_ __attribute__((ext_vector_type(2)));

__device__ __forceinline__ float sigmoidf_(float x){ return 1.0f/(1.0f + __expf(-x)); }

__device__ __forceinline__ float dot2u_(uint a, uint b, float c){
#if __has_builtin(__builtin_amdgcn_fdot2)
  return __builtin_amdgcn_fdot2(*(half2_*)&a, *(half2_*)&b, c, false);
#else
  half2_ ha = *(half2_*)&a, hb = *(half2_*)&b;
  c = fmaf((float)ha.x, (float)hb.x, c);
  return fmaf((float)ha.y, (float)hb.y, c);
#endif
}

__device__ __forceinline__ float dot2h_(half2_ a, half2_ b, float c){
#if __has_builtin(__builtin_amdgcn_fdot2)
  return __builtin_amdgcn_fdot2(a, b, c, false);
#else
  c = fmaf((float)a.x, (float)b.x, c);
  return fmaf((float)a.y, (float)b.y, c);
#endif
}

// Build |sound| fp16 pair arrays (even-start pA, odd-start pB) + fp16 weight pairs.
__global__ void k_prep16(const float* __restrict__ sound, const float* __restrict__ w,
                         uint* __restrict__ pA, uint* __restrict__ pB,
                         uint* __restrict__ wp){
  const int stride = gridDim.x*blockDim.x;
  for (int i = blockIdx.x*blockDim.x + threadIdx.x; i < PAIRS + 9*WPROW; i += stride){
    if (i < PAIRS){
      int e0 = 2*i - FR2;
      float v0 = (e0 >= 0     && e0 < LSND)     ? fabsf(sound[e0])   : 0.0f;
      float v1 = (e0+1 >= 0   && e0+1 < LSND)   ? fabsf(sound[e0+1]) : 0.0f;
      float v2 = (e0+2 >= 0   && e0+2 < LSND)   ? fabsf(sound[e0+2]) : 0.0f;
      half2_ a = { (_Float16)v0, (_Float16)v1 };
      half2_ b = { (_Float16)v1, (_Float16)v2 };
      pA[i] = *(uint*)&a;
      pB[i] = *(uint*)&b;
    } else {
      int p = i - PAIRS;
      int k = p / WPROW, pr = p % WPROW;
      int j = 2*pr;
      float v0 = (j   < FRLEN) ? w[k*FRLEN + j]   : 0.0f;
      float v1 = (j+1 < FRLEN) ? w[k*FRLEN + j+1] : 0.0f;
      half2_ a = { (_Float16)v0, (_Float16)v1 };
      wp[i - PAIRS] = *(uint*)&a;
    }
  }
}

// Fused front-end: gi matmul + GRU pointwise + convs + linear + LSTM input proj.
__global__ __launch_bounds__(512, 2) void k_front(const uint* __restrict__ pA,
    const uint* __restrict__ pB, const uint* __restrict__ wp,
    const int* __restrict__ alpha,
    const float* __restrict__ gbih, const float* __restrict__ gbhh,
    const float* __restrict__ c2w, const float* __restrict__ c2b,
    const float* __restrict__ c3w, const float* __restrict__ c3b,
    const float* __restrict__ lw, const float* __restrict__ lb,
    const float* __restrict__ wih, const float* __restrict__ bih, const float* __restrict__ bhh,
    _Float16* __restrict__ pre){
  const int tid = threadIdx.x;
  const int row0 = blockIdx.x * ROWS;
  const uint* hp[ROWS];
  int idx0[ROWS];
#pragma unroll
  for (int r = 0; r < ROWS; ++r){
    int b = alpha[row0 + r];
    hp[r] = (b & 1) ? pB : pA;
    idx0[r] = b >> 1;
  }
  float acc[ROWS][9];
#pragma unroll
  for (int r = 0; r < ROWS; ++r)
#pragma unroll
    for (int k = 0; k < 9; ++k) acc[r][k] = 0.0f;

  for (int jj = tid; jj < NJP; jj += 512){
    const int jp = jj*4;
    uint4 f[ROWS];
#pragma unroll
    for (int r = 0; r < ROWS; ++r){
      const uint* p = hp[r] + idx0[r] + jp;
      f[r].x = p[0]; f[r].y = p[1]; f[r].z = p[2]; f[r].w = p[3];
    }
#pragma unroll
    for (int k = 0; k < 9; ++k){
      const uint4 wq = *reinterpret_cast<const uint4*>(wp + k*WPROW + jp);
#pragma unroll
      for (int r = 0; r < ROWS; ++r){
        acc[r][k] = dot2u_(f[r].x, wq.x, acc[r][k]);
        acc[r][k] = dot2u_(f[r].y, wq.y, acc[r][k]);
        acc[r][k] = dot2u_(f[r].z, wq.z, acc[r][k]);
        acc[r][k] = dot2u_(f[r].w, wq.w, acc[r][k]);
      }
    }
  }
#pragma unroll
  for (int m = 32; m >= 1; m >>= 1){
#pragma unroll
    for (int r = 0; r < ROWS; ++r)
#pragma unroll
      for (int k = 0; k < 9; ++k)
        acc[r][k] += __shfl_xor(acc[r][k], m, 64);
  }
  __shared__ float red[8][ROWS*9];
  __shared__ float sgi[ROWS*9];
  const int wv_ = tid >> 6, ln = tid & 63;
  if (ln == 0){
#pragma unroll
    for (int r = 0; r < ROWS; ++r)
#pragma unroll
      for (int k = 0; k < 9; ++k) red[wv_][r*9+k] = acc[r][k];
  }
  __syncthreads();
  if (tid < ROWS*9){
    float s = 0.0f;
#pragma unroll
    for (int q = 0; q < 8; ++q) s += red[q][tid];
    sgi[tid] = s;
  }
  __syncthreads();
  if (tid < ROWS){
    const int t = row0 + tid;
    float gi[9];
#pragma unroll
    for (int k = 0; k < 9; ++k) gi[k] = sgi[tid*9+k] + gbih[k];
    float h[3];
#pragma unroll
    for (int q = 0; q < 3; ++q){
      float rr = sigmoidf_(gi[q]   + gbhh[q]);
      float zz = sigmoidf_(gi[3+q] + gbhh[3+q]);
      float nn = tanhf(gi[6+q] + rr*gbhh[6+q]);
      h[q] = (1.0f - zz)*nn;
    }
    float feat[16];
#pragma unroll
    for (int c = 0; c < 16; ++c) feat[c] = c3b[c];
    for (int ic = 0; ic < 32; ++ic){
      float w0 = c2w[ic*3+0], w1 = c2w[ic*3+1], w2 = c2w[ic*3+2], bb = c2b[ic];
      float x0 = fmaxf(bb + h[0]*w1 + h[1]*w2, 0.0f);
      float x1 = fmaxf(bb + h[0]*w0 + h[1]*w1 + h[2]*w2, 0.0f);
      float x2_ = fmaxf(bb + h[1]*w0 + h[2]*w1, 0.0f);
#pragma unroll
      for (int c = 0; c < 16; ++c){
        const float* wpp = c3w + (c*32+ic)*3;
        feat[c] += x0*wpp[0] + x1*wpp[1] + x2_*wpp[2];
      }
    }
    float interval = (float)(t == 0 ? alpha[0] : (alpha[t] - alpha[t-1]));
    float xin[10];
#pragma unroll
    for (int k = 0; k < 10; ++k){
      float s = lb[k] + interval*lw[k*17];
#pragma unroll
      for (int j = 0; j < 16; ++j) s = fmaf(feat[j], lw[k*17+1+j], s);
      xin[k] = s;
    }
#pragma unroll
    for (int k = 0; k < 40; ++k){
      float s = bih[k] + bhh[k];
#pragma unroll
      for (int i = 0; i < 10; ++i) s = fmaf(xin[i], wih[k*10+i], s);
      const float sc = (k >= 20 && k < 30) ? (-2.0f*LOG2E) : (-LOG2E);
      pre[t*40 + k] = (_Float16)(s * sc);
    }
  }
}

// One LSTM step. Gate dot = 5 dot2 (fp16 pairs, fp32 acc); h re-broadcast as
// packed half2 via DPP(row_shr:1)+cvt_pkrtz then 5 readlanes.
#define LSTM_STEP(PREFETCH_STMT)                                              \
  {                                                                           \
    float g = (float)q0;                                                      \
    q0 = q1; q1 = q2; q2 = q3;                                                \
    PREFETCH_STMT;                                                            \
    float ga = dot2h_(wpk0, hp0, g);                                          \
    ga = dot2h_(wpk1, hp1, ga);                                               \
    ga = dot2h_(wpk2, hp2, ga);                                               \
    float gb = dot2h_(wpk3, hp3, 0.0f);                                       \
    gb = dot2h_(wpk4, hp4, gb);                                               \
    g = ga + gb;                                                              \
    float act = fmaf(__builtin_amdgcn_rcpf(1.0f + __builtin_amdgcn_exp2f(g)), s2, s3); \
    float g_sw = act;                                                         \
    asm("v_permlane32_swap_b32 %0, %1" : "+v"(act), "+v"(g_sw));              \
    float f_sw = act;                                                         \
    asm("v_permlane16_swap_b32 %0, %1" : "+v"(act), "+v"(f_sw));              \
    float o_sw = g_sw;                                                        \
    asm("v_permlane16_swap_b32 %0, %1" : "+v"(g_sw), "+v"(o_sw));             \
    float ig = act * g_sw;                                                    \
    c = fmaf(f_sw, c, ig);                                                    \
    float th = fmaf(__builtin_amdgcn_rcpf(1.0f + __builtin_amdgcn_exp2f(c)), 2.0f, -1.0f); \
    float hn = o_sw * th;                                                     \
    int hni = __float_as_int(hn);                                             \
    int hnx = __builtin_amdgcn_update_dpp(0, hni, 0x111, 0xf, 0xf, true);     \
    auto hpk = __builtin_amdgcn_cvt_pkrtz(hn, __int_as_float(hnx));           \
    int pki = *(int*)&hpk;                                                    \
    { int _r = __builtin_amdgcn_readlane(pki, 0); hp0 = *(half2_*)&_r; }      \
    { int _r = __builtin_amdgcn_readlane(pki, 2); hp1 = *(half2_*)&_r; }      \
    { int _r = __builtin_amdgcn_readlane(pki, 4); hp2 = *(half2_*)&_r; }      \
    { int _r = __builtin_amdgcn_readlane(pki, 6); hp3 = *(half2_*)&_r; }      \
    { int _r = __builtin_amdgcn_readlane(pki, 8); hp4 = *(half2_*)&_r; }      \
  }

__global__ __launch_bounds__(1024, 1) void k_lstm(const _Float16* __restrict__ pre,
                       const float* __restrict__ whh,
                       const float* __restrict__ l1w, const float* __restrict__ l1b,
                       const float* __restrict__ l2w, const float* __restrict__ l2b,
                       float* __restrict__ out){
  extern __shared__ _Float16 sp[];   // sp[t*40 + gate*10 + unit], pre-scaled
  {
    uint4* dst = (uint4*)sp;
    const uint4* src = (const uint4*)pre;
    for (int i = threadIdx.x; i < (TSTEPS*40*2)/16; i += 1024) dst[i] = src[i];
  }
  __syncthreads();
  if (threadIdx.x >= 64) return;

  const int lane = threadIdx.x;
  const int gate = lane >> 4;
  const int unit_raw = lane & 15;
  const int unit = unit_raw < 10 ? unit_raw : 9;
  const int L40 = gate*10 + unit;
  const bool is_g = (gate == 2);
  const float kk  = -2.0f*LOG2E;
  const float wsc = is_g ? kk : (-LOG2E);
  const float s2  = is_g ? (2.0f*kk) : 1.0f;
  const float s3  = is_g ? (-kk)     : 0.0f;
  // packed fp16 recurrence weights (pre-scaled)
  half2_ wpk0, wpk1, wpk2, wpk3, wpk4;
  {
    const float* wr = whh + L40*10;
    wpk0 = { (_Float16)(wr[0]*wsc), (_Float16)(wr[1]*wsc) };
    wpk1 = { (_Float16)(wr[2]*wsc), (_Float16)(wr[3]*wsc) };
    wpk2 = { (_Float16)(wr[4]*wsc), (_Float16)(wr[5]*wsc) };
    wpk3 = { (_Float16)(wr[6]*wsc), (_Float16)(wr[7]*wsc) };
    wpk4 = { (_Float16)(wr[8]*wsc), (_Float16)(wr[9]*wsc) };
  }
  half2_ hz = { (_Float16)0.0f, (_Float16)0.0f };
  half2_ hp0 = hz, hp1 = hz, hp2 = hz, hp3 = hz, hp4 = hz;
  float c = 0.0f;

  _Float16 q0 = sp[0*40+L40], q1 = sp[1*40+L40], q2 = sp[2*40+L40], q3 = sp[3*40+L40];
#pragma unroll 4
  for (int t = 0; t < TSTEPS-4; ++t){
    LSTM_STEP(q3 = sp[(t+4)*40 + L40]);
  }
#pragma unroll
  for (int t = TSTEPS-4; t < TSTEPS; ++t){
    LSTM_STEP(;);
  }
  // unpack final h
  float hf[10];
  hf[0]=(float)hp0.x; hf[1]=(float)hp0.y; hf[2]=(float)hp1.x; hf[3]=(float)hp1.y;
  hf[4]=(float)hp2.x; hf[5]=(float)hp2.y; hf[6]=(float)hp3.x; hf[7]=(float)hp3.y;
  hf[8]=(float)hp4.x; hf[9]=(float)hp4.y;
  float z = 0.0f;
  if (lane < 32){
    float s = l1b[lane];
#pragma unroll
    for (int i = 0; i < 10; ++i) s = fmaf(hf[i], l1w[lane*10+i], s);
    z = fmaxf(s, 0.0f) * l2w[lane];
  }
#pragma unroll
  for (int m = 32; m >= 1; m >>= 1) z += __shfl_xor(z, m, 64);
  if (lane == 0) out[0] = sigmoidf_(z + l2b[0]);
}

extern "C" void kernel_launch(void* const* d_in, const int* in_sizes, int n_in,
                              void* d_out, int out_size, void* d_ws, size_t ws_size,
                              hipStream_t stream){
  const float* sound     = (const float*)d_in[0];
  const int*   alpha     = (const int*)  d_in[1];
  const float* gru_w_ih  = (const float*)d_in[2];
  const float* gru_b_ih  = (const float*)d_in[3];
  const float* gru_b_hh  = (const float*)d_in[4];
  const float* conv2_w   = (const float*)d_in[5];
  const float* conv2_b   = (const float*)d_in[6];
  const float* conv3_w   = (const float*)d_in[7];
  const float* conv3_b   = (const float*)d_in[8];
  const float* lin_w     = (const float*)d_in[9];
  const float* lin_b     = (const float*)d_in[10];
  const float* lstm_w_ih = (const float*)d_in[11];
  const float* lstm_w_hh = (const float*)d_in[12];
  const float* lstm_b_ih = (const float*)d_in[13];
  const float* lstm_b_hh = (const float*)d_in[14];
  const float* lin1_w    = (const float*)d_in[15];
  const float* lin1_b    = (const float*)d_in[16];
  const float* lin2_w    = (const float*)d_in[17];
  const float* lin2_b    = (const float*)d_in[18];

  char* ws = (char*)d_ws;
  uint* pA      = (uint*)ws;                         // PAIRS uints
  uint* pB      = pA + PAIRS;                        // PAIRS uints
  uint* wpairs  = pB + PAIRS;                        // 9*WPROW uints
  _Float16* pre = (_Float16*)(wpairs + 9*WPROW);     // T*40 fp16

  (void)hipFuncSetAttribute((const void*)k_lstm,
        hipFuncAttributeMaxDynamicSharedMemorySize, TSTEPS*40*2);

  hipLaunchKernelGGL(k_prep16, dim3(1536), dim3(256), 0, stream,
                     sound, gru_w_ih, pA, pB, wpairs);
  hipLaunchKernelGGL(k_front, dim3(TSTEPS/ROWS), dim3(512), 0, stream,
                     pA, pB, wpairs, alpha,
                     gru_b_ih, gru_b_hh, conv2_w, conv2_b, conv3_w, conv3_b,
                     lin_w, lin_b, lstm_w_ih, lstm_b_ih, lstm_b_hh, pre);
  hipLaunchKernelGGL(k_lstm, dim3(1), dim3(1024), TSTEPS*40*2, stream,
                     pre, lstm_w_hh, lin1_w, lin1_b, lin2_w, lin2_b, (float*)d_out);
}

// Round 10
// 245.507 us; speedup vs baseline: 2.8640x; 1.0068x over previous
//
#include <hip/hip_runtime.h>

#define FRLEN 44100
#define FR2 22050
#define LSND 882000
#define TSTEPS 2048
#define ROWS 8
#define LOG2E 1.4426950408889634f

#define KPAD 44104              // K rounded up to 8
#define WPROW (KPAD/2)          // 22052 pairs per weight row
#define NJP (WPROW/4)           // 5513 quad-pair iterations
#define PAIRS 463056            // half2 pairs in pA/pB (covers padded range+slack)
#define NGS (PAIRS/4)           // 115764 sound groups (4 pairs each)
#define WGRP (WPROW/4)          // 5513 weight groups per row
#define NGW (9*WGRP)            // 49617 weight groups

typedef _Float16 half2_ __attribute__((ext_vector_type(2)));

__device__ __forceinline__ float sigmoidf_(float x){ return 1.0f/(1.0f + __expf(-x)); }

__device__ __forceinline__ float dot2u_(uint a, uint b, float c){
#if __has_builtin(__builtin_amdgcn_fdot2)
  return __builtin_amdgcn_fdot2(*(half2_*)&a, *(half2_*)&b, c, false);
#else
  half2_ ha = *(half2_*)&a, hb = *(half2_*)&b;
  c = fmaf((float)ha.x, (float)hb.x, c);
  return fmaf((float)ha.y, (float)hb.y, c);
#endif
}

__device__ __forceinline__ float dot2h_(half2_ a, half2_ b, float c){
#if __has_builtin(__builtin_amdgcn_fdot2)
  return __builtin_amdgcn_fdot2(a, b, c, false);
#else
  c = fmaf((float)a.x, (float)b.x, c);
  return fmaf((float)a.y, (float)b.y, c);
#endif
}

__device__ __forceinline__ uint pk_(float a, float b){
  auto p = __builtin_amdgcn_cvt_pkrtz(a, b);
  return *(uint*)&p;
}

// Vectorized prep: 4 pairs (8-9 elements) per thread.
__global__ void k_prep16(const float* __restrict__ sound, const float* __restrict__ w,
                         uint* __restrict__ pA, uint* __restrict__ pB,
                         uint* __restrict__ wp){
  const int i = blockIdx.x*blockDim.x + threadIdx.x;
  if (i < NGS){
    const int p0 = i*4;
    const int e0 = 2*p0 - FR2;
    float v[9];
    if (e0 >= 0 && e0 + 8 < LSND){
#pragma unroll
      for (int k = 0; k < 9; ++k) v[k] = fabsf(sound[e0+k]);
    } else {
#pragma unroll
      for (int k = 0; k < 9; ++k){
        int e = e0 + k;
        v[k] = (e >= 0 && e < LSND) ? fabsf(sound[e]) : 0.0f;
      }
    }
    uint4 a = make_uint4(pk_(v[0],v[1]), pk_(v[2],v[3]), pk_(v[4],v[5]), pk_(v[6],v[7]));
    uint4 b = make_uint4(pk_(v[1],v[2]), pk_(v[3],v[4]), pk_(v[5],v[6]), pk_(v[7],v[8]));
    *reinterpret_cast<uint4*>(pA + p0) = a;
    *reinterpret_cast<uint4*>(pB + p0) = b;
  } else if (i < NGS + NGW){
    const int g = i - NGS;
    const int k = g / WGRP, gg = g % WGRP;
    const int j = gg*8;
    float v[8];
    if (j + 8 <= FRLEN){
      float4 x = *reinterpret_cast<const float4*>(w + k*FRLEN + j);
      float4 y = *reinterpret_cast<const float4*>(w + k*FRLEN + j + 4);
      v[0]=x.x; v[1]=x.y; v[2]=x.z; v[3]=x.w; v[4]=y.x; v[5]=y.y; v[6]=y.z; v[7]=y.w;
    } else {
#pragma unroll
      for (int q = 0; q < 8; ++q) v[q] = (j+q < FRLEN) ? w[k*FRLEN + j + q] : 0.0f;
    }
    *reinterpret_cast<uint4*>(wp + k*WPROW + gg*4) =
        make_uint4(pk_(v[0],v[1]), pk_(v[2],v[3]), pk_(v[4],v[5]), pk_(v[6],v[7]));
  }
}

// Fused front-end with frag/weight prefetch (latency hidden under dot2 compute).
__global__ __launch_bounds__(512, 2) void k_front(const uint* __restrict__ pA,
    const uint* __restrict__ pB, const uint* __restrict__ wp,
    const int* __restrict__ alpha,
    const float* __restrict__ gbih, const float* __restrict__ gbhh,
    const float* __restrict__ c2w, const float* __restrict__ c2b,
    const float* __restrict__ c3w, const float* __restrict__ c3b,
    const float* __restrict__ lw, const float* __restrict__ lb,
    const float* __restrict__ wih, const float* __restrict__ bih, const float* __restrict__ bhh,
    _Float16* __restrict__ pre){
  const int tid = threadIdx.x;
  const int row0 = blockIdx.x * ROWS;
  const uint* bp[ROWS];
#pragma unroll
  for (int r = 0; r < ROWS; ++r){
    int b = alpha[row0 + r];
    bp[r] = ((b & 1) ? pB : pA) + (b >> 1);
  }
  float acc[ROWS][9];
#pragma unroll
  for (int r = 0; r < ROWS; ++r)
#pragma unroll
    for (int k = 0; k < 9; ++k) acc[r][k] = 0.0f;

  uint4 fcur[ROWS];
  {
    const int jp = tid*4;
#pragma unroll
    for (int r = 0; r < ROWS; ++r){
      const uint* p = bp[r] + jp;
      fcur[r] = make_uint4(p[0], p[1], p[2], p[3]);
    }
  }
  for (int jj = tid; jj < NJP; jj += 512){
    const int jn = jj + 512;
    uint4 fnx[ROWS];
    if (jn < NJP){
      const int jp2 = jn*4;
#pragma unroll
      for (int r = 0; r < ROWS; ++r){
        const uint* p = bp[r] + jp2;
        fnx[r] = make_uint4(p[0], p[1], p[2], p[3]);
      }
    } else {
#pragma unroll
      for (int r = 0; r < ROWS; ++r) fnx[r] = fcur[r];
    }
    const int jp = jj*4;
    uint4 wq = *reinterpret_cast<const uint4*>(wp + jp);
#pragma unroll
    for (int k = 0; k < 9; ++k){
      uint4 wqn;
      if (k < 8) wqn = *reinterpret_cast<const uint4*>(wp + (k+1)*WPROW + jp);
#pragma unroll
      for (int r = 0; r < ROWS; ++r){
        acc[r][k] = dot2u_(fcur[r].x, wq.x, acc[r][k]);
        acc[r][k] = dot2u_(fcur[r].y, wq.y, acc[r][k]);
        acc[r][k] = dot2u_(fcur[r].z, wq.z, acc[r][k]);
        acc[r][k] = dot2u_(fcur[r].w, wq.w, acc[r][k]);
      }
      if (k < 8) wq = wqn;
    }
#pragma unroll
    for (int r = 0; r < ROWS; ++r) fcur[r] = fnx[r];
  }
#pragma unroll
  for (int m = 32; m >= 1; m >>= 1){
#pragma unroll
    for (int r = 0; r < ROWS; ++r)
#pragma unroll
      for (int k = 0; k < 9; ++k)
        acc[r][k] += __shfl_xor(acc[r][k], m, 64);
  }
  __shared__ float red[8][ROWS*9];
  __shared__ float sgi[ROWS*9];
  const int wv_ = tid >> 6, ln = tid & 63;
  if (ln == 0){
#pragma unroll
    for (int r = 0; r < ROWS; ++r)
#pragma unroll
      for (int k = 0; k < 9; ++k) red[wv_][r*9+k] = acc[r][k];
  }
  __syncthreads();
  if (tid < ROWS*9){
    float s = 0.0f;
#pragma unroll
    for (int q = 0; q < 8; ++q) s += red[q][tid];
    sgi[tid] = s;
  }
  __syncthreads();
  if (tid < ROWS){
    const int t = row0 + tid;
    float gi[9];
#pragma unroll
    for (int k = 0; k < 9; ++k) gi[k] = sgi[tid*9+k] + gbih[k];
    float h[3];
#pragma unroll
    for (int q = 0; q < 3; ++q){
      float rr = sigmoidf_(gi[q]   + gbhh[q]);
      float zz = sigmoidf_(gi[3+q] + gbhh[3+q]);
      float nn = tanhf(gi[6+q] + rr*gbhh[6+q]);
      h[q] = (1.0f - zz)*nn;
    }
    float feat[16];
#pragma unroll
    for (int c = 0; c < 16; ++c) feat[c] = c3b[c];
    for (int ic = 0; ic < 32; ++ic){
      float w0 = c2w[ic*3+0], w1 = c2w[ic*3+1], w2 = c2w[ic*3+2], bb = c2b[ic];
      float x0 = fmaxf(bb + h[0]*w1 + h[1]*w2, 0.0f);
      float x1 = fmaxf(bb + h[0]*w0 + h[1]*w1 + h[2]*w2, 0.0f);
      float x2_ = fmaxf(bb + h[1]*w0 + h[2]*w1, 0.0f);
#pragma unroll
      for (int c = 0; c < 16; ++c){
        const float* wpp = c3w + (c*32+ic)*3;
        feat[c] += x0*wpp[0] + x1*wpp[1] + x2_*wpp[2];
      }
    }
    float interval = (float)(t == 0 ? alpha[0] : (alpha[t] - alpha[t-1]));
    float xin[10];
#pragma unroll
    for (int k = 0; k < 10; ++k){
      float s = lb[k] + interval*lw[k*17];
#pragma unroll
      for (int j = 0; j < 16; ++j) s = fmaf(feat[j], lw[k*17+1+j], s);
      xin[k] = s;
    }
#pragma unroll
    for (int k = 0; k < 40; ++k){
      float s = bih[k] + bhh[k];
#pragma unroll
      for (int i = 0; i < 10; ++i) s = fmaf(xin[i], wih[k*10+i], s);
      const float sc = (k >= 20 && k < 30) ? (-2.0f*LOG2E) : (-LOG2E);
      pre[t*40 + k] = (_Float16)(s * sc);
    }
  }
}

// One LSTM step. 5 dot2 + 1 trans-act; h broadcast as packed half2.
#define LSTM_STEP(PREFETCH_STMT)                                              \
  {                                                                           \
    float g = (float)q0;                                                      \
    q0 = q1; q1 = q2; q2 = q3;                                                \
    PREFETCH_STMT;                                                            \
    float ga = dot2h_(wpk0, hp0, g);                                          \
    ga = dot2h_(wpk1, hp1, ga);                                               \
    ga = dot2h_(wpk2, hp2, ga);                                               \
    float gb = dot2h_(wpk3, hp3, 0.0f);                                       \
    gb = dot2h_(wpk4, hp4, gb);                                               \
    g = ga + gb;                                                              \
    float act = fmaf(__builtin_amdgcn_rcpf(1.0f + __builtin_amdgcn_exp2f(g)), s2, s3); \
    float g_sw = act;                                                         \
    asm("v_permlane32_swap_b32 %0, %1" : "+v"(act), "+v"(g_sw));              \
    float f_sw = act;                                                         \
    asm("v_permlane16_swap_b32 %0, %1" : "+v"(act), "+v"(f_sw));              \
    float o_sw = g_sw;                                                        \
    asm("v_permlane16_swap_b32 %0, %1" : "+v"(g_sw), "+v"(o_sw));             \
    float ig = act * g_sw;                                                    \
    c = fmaf(f_sw, c, ig);                                                    \
    float o2 = o_sw + o_sw;                                                   \
    float hn = fmaf(__builtin_amdgcn_rcpf(1.0f + __builtin_amdgcn_exp2f(c)), o2, -o_sw); \
    int hni = __float_as_int(hn);                                             \
    int hnx = __builtin_amdgcn_update_dpp(0, hni, 0x111, 0xf, 0xf, true);     \
    auto hpk = __builtin_amdgcn_cvt_pkrtz(hn, __int_as_float(hnx));           \
    int pki = *(int*)&hpk;                                                    \
    { int _r = __builtin_amdgcn_readlane(pki, 0); hp0 = *(half2_*)&_r; }      \
    { int _r = __builtin_amdgcn_readlane(pki, 2); hp1 = *(half2_*)&_r; }      \
    { int _r = __builtin_amdgcn_readlane(pki, 4); hp2 = *(half2_*)&_r; }      \
    { int _r = __builtin_amdgcn_readlane(pki, 6); hp3 = *(half2_*)&_r; }      \
    { int _r = __builtin_amdgcn_readlane(pki, 8); hp4 = *(half2_*)&_r; }      \
  }

__global__ __launch_bounds__(1024, 1) void k_lstm(const _Float16* __restrict__ pre,
                       const float* __restrict__ whh,
                       const float* __restrict__ l1w, const float* __restrict__ l1b,
                       const float* __restrict__ l2w, const float* __restrict__ l2b,
                       float* __restrict__ out){
  extern __shared__ _Float16 sp[];   // sp[t*40 + gate*10 + unit], pre-scaled
  {
    uint4* dst = (uint4*)sp;
    const uint4* src = (const uint4*)pre;
    for (int i = threadIdx.x; i < (TSTEPS*40*2)/16; i += 1024) dst[i] = src[i];
  }
  __syncthreads();
  if (threadIdx.x >= 64) return;

  const int lane = threadIdx.x;
  const int gate = lane >> 4;
  const int unit_raw = lane & 15;
  const int unit = unit_raw < 10 ? unit_raw : 9;
  const int L40 = gate*10 + unit;
  const bool is_g = (gate == 2);
  const float kk  = -2.0f*LOG2E;
  const float wsc = is_g ? kk : (-LOG2E);
  const float s2  = is_g ? (2.0f*kk) : 1.0f;
  const float s3  = is_g ? (-kk)     : 0.0f;
  half2_ wpk0, wpk1, wpk2, wpk3, wpk4;
  {
    const float* wr = whh + L40*10;
    wpk0 = { (_Float16)(wr[0]*wsc), (_Float16)(wr[1]*wsc) };
    wpk1 = { (_Float16)(wr[2]*wsc), (_Float16)(wr[3]*wsc) };
    wpk2 = { (_Float16)(wr[4]*wsc), (_Float16)(wr[5]*wsc) };
    wpk3 = { (_Float16)(wr[6]*wsc), (_Float16)(wr[7]*wsc) };
    wpk4 = { (_Float16)(wr[8]*wsc), (_Float16)(wr[9]*wsc) };
  }
  half2_ hz = { (_Float16)0.0f, (_Float16)0.0f };
  half2_ hp0 = hz, hp1 = hz, hp2 = hz, hp3 = hz, hp4 = hz;
  float c = 0.0f;

  _Float16 q0 = sp[0*40+L40], q1 = sp[1*40+L40], q2 = sp[2*40+L40], q3 = sp[3*40+L40];
#pragma unroll 4
  for (int t = 0; t < TSTEPS-4; ++t){
    LSTM_STEP(q3 = sp[(t+4)*40 + L40]);
  }
#pragma unroll
  for (int t = TSTEPS-4; t < TSTEPS; ++t){
    LSTM_STEP(;);
  }
  float hf[10];
  hf[0]=(float)hp0.x; hf[1]=(float)hp0.y; hf[2]=(float)hp1.x; hf[3]=(float)hp1.y;
  hf[4]=(float)hp2.x; hf[5]=(float)hp2.y; hf[6]=(float)hp3.x; hf[7]=(float)hp3.y;
  hf[8]=(float)hp4.x; hf[9]=(float)hp4.y;
  float z = 0.0f;
  if (lane < 32){
    float s = l1b[lane];
#pragma unroll
    for (int i = 0; i < 10; ++i) s = fmaf(hf[i], l1w[lane*10+i], s);
    z = fmaxf(s, 0.0f) * l2w[lane];
  }
#pragma unroll
  for (int m = 32; m >= 1; m >>= 1) z += __shfl_xor(z, m, 64);
  if (lane == 0) out[0] = sigmoidf_(z + l2b[0]);
}

extern "C" void kernel_launch(void* const* d_in, const int* in_sizes, int n_in,
                              void* d_out, int out_size, void* d_ws, size_t ws_size,
                              hipStream_t stream){
  const float* sound     = (const float*)d_in[0];
  const int*   alpha     = (const int*)  d_in[1];
  const float* gru_w_ih  = (const float*)d_in[2];
  const float* gru_b_ih  = (const float*)d_in[3];
  const float* gru_b_hh  = (const float*)d_in[4];
  const float* conv2_w   = (const float*)d_in[5];
  const float* conv2_b   = (const float*)d_in[6];
  const float* conv3_w   = (const float*)d_in[7];
  const float* conv3_b   = (const float*)d_in[8];
  const float* lin_w     = (const float*)d_in[9];
  const float* lin_b     = (const float*)d_in[10];
  const float* lstm_w_ih = (const float*)d_in[11];
  const float* lstm_w_hh = (const float*)d_in[12];
  const float* lstm_b_ih = (const float*)d_in[13];
  const float* lstm_b_hh = (const float*)d_in[14];
  const float* lin1_w    = (const float*)d_in[15];
  const float* lin1_b    = (const float*)d_in[16];
  const float* lin2_w    = (const float*)d_in[17];
  const float* lin2_b    = (const float*)d_in[18];

  char* ws = (char*)d_ws;
  uint* pA      = (uint*)ws;                         // PAIRS uints
  uint* pB      = pA + PAIRS;                        // PAIRS uints
  uint* wpairs  = pB + PAIRS;                        // 9*WPROW uints
  _Float16* pre = (_Float16*)(wpairs + 9*WPROW);     // T*40 fp16

  (void)hipFuncSetAttribute((const void*)k_lstm,
        hipFuncAttributeMaxDynamicSharedMemorySize, TSTEPS*40*2);

  hipLaunchKernelGGL(k_prep16, dim3((NGS + NGW + 255)/256), dim3(256), 0, stream,
                     sound, gru_w_ih, pA, pB, wpairs);
  hipLaunchKernelGGL(k_front, dim3(TSTEPS/ROWS), dim3(512), 0, stream,
                     pA, pB, wpairs, alpha,
                     gru_b_ih, gru_b_hh, conv2_w, conv2_b, conv3_w, conv3_b,
                     lin_w, lin_b, lstm_w_ih, lstm_b_ih, lstm_b_hh, pre);
  hipLaunchKernelGGL(k_lstm, dim3(1), dim3(1024), TSTEPS*40*2, stream,
                     pre, lstm_w_hh, lin1_w, lin1_b, lin2_w, lin2_b, (float*)d_out);
}